// Round 10
// baseline (935.309 us; speedup 1.0000x reference)
//
// v17: attnA K/V LDS-shared staging. v16 post-mortem: unroll-2 gave exactly
// its 17%; remaining serialization is the 8 row-gather loads/iter (16 cache
// lines each) with only 2-deep cover. All 4 waves read IDENTICAL K/V tiles
// (same head) -> stage to LDS once, coalesced (256 thr x 16B = one tile),
// double-buffered, ONE barrier/iter (store->buf^1 vs read->buf ordered by the
// end-of-body barrier), tile mt+2 loads issued mid-body (one body of latency
// hiding). Padded LDS rows (66/34) keep frag reads <=2-way. prt single-buf
// (barrier orders reuse). Everything else verbatim from verified v16.
#include <hip/hip_runtime.h>

typedef unsigned short u16;
typedef unsigned int   u32;
typedef unsigned char  u8;
typedef __attribute__((ext_vector_type(8))) short          short8;
typedef __attribute__((ext_vector_type(8))) unsigned short ushort8;
typedef __attribute__((ext_vector_type(4))) float          f32x4;

#define MFMA(a,b,c) __builtin_amdgcn_mfma_f32_16x16x32_bf16((a),(b),(c),0,0,0)
#define Nx 2048
#define Dx 1024
#define SCALEx 0.125f
#define L2E 1.4426950408889634f

__device__ __forceinline__ float bf2f(u16 u){ u32 x=((u32)u)<<16; return __builtin_bit_cast(float,x); }
__device__ __forceinline__ u16 f2bf(float f){ u32 u=__builtin_bit_cast(u32,f); u32 r=(u+0x7FFFu+((u>>16)&1u))>>16; return (u16)r; }
__device__ __forceinline__ short8 lds8(const u16* p){ return *(const short8*)p; }

// ---- dtype normalization (identity if already bf16) ----
__device__ int looks_bf16_dev(const u16* p, int nsamp, float lo, float hi){
  int cnt = 0;
  for (int i = 0; i < nsamp; ++i){
    float a = fabsf(bf2f(p[2*i]));
    if (a >= lo && a <= hi) cnt++;
  }
  return (2*cnt > nsamp) ? 1 : 0;
}

__global__ __launch_bounds__(256) void conv_w(const void* __restrict__ in, u16* __restrict__ S,
                                              int n, int nsamp, float lo, float hi){
  __shared__ int flag;
  if (threadIdx.x == 0) flag = looks_bf16_dev((const u16*)in, nsamp, lo, hi);
  __syncthreads();
  const int isbf = flag;
  int i = blockIdx.x*256 + threadIdx.x;
  int stride = gridDim.x*256;
  if (isbf){
    const u16* pu = (const u16*)in;
    for (; i < n; i += stride) S[i] = pu[i];
  } else {
    const float* pf = (const float*)in;
    for (; i < n; i += stride) S[i] = f2bf(pf[i]);
  }
}

__global__ __launch_bounds__(256) void copyb(const u16* __restrict__ S, u16* __restrict__ dst, int n){
  int i = blockIdx.x*256 + threadIdx.x;
  int stride = gridDim.x*256;
  for (; i < n; i += stride) dst[i] = S[i];
}

__global__ void conv_small(void* buf, int n, float lo, float hi){
  __shared__ float tmp[64];
  __shared__ int flag;
  int t = threadIdx.x;
  if (t == 0) flag = looks_bf16_dev((const u16*)buf, n/2, lo, hi);
  __syncthreads();
  if (t < n) tmp[t] = flag ? bf2f(((const u16*)buf)[t]) : ((const float*)buf)[t];
  __syncthreads();
  if (t < n) ((u16*)buf)[t] = f2bf(tmp[t]);
}

// ---------------------------------------------------------------------------
// NT GEMM bf16: C[M][ldc] = ascale * (A[M][1024] @ Bt[N][1024]^T)
// ---------------------------------------------------------------------------
__global__ __launch_bounds__(256) void gemm_bf16(
    const u16* __restrict__ A, const u16* __restrict__ Bt, u16* __restrict__ C,
    int ldc, float ascale)
{
  const int tid = threadIdx.x;
  const int lane = tid & 63, wave = tid >> 6;
  const int wm = wave >> 1, wn = wave & 1;
  const int l15 = lane & 15, quad = lane >> 4;
  const int m0 = blockIdx.y * 128, n0 = blockIdx.x * 128;
  __shared__ u16 As[128*32], Bs[128*32];
  f32x4 acc[4][4] = {};
  const int srow0 = tid >> 2, scol = tid & 3;
  const int srow1 = (tid + 256) >> 2;
  for (int k0 = 0; k0 < 1024; k0 += 32) {
    ushort8 a0 = *(const ushort8*)&A [(size_t)(m0 + srow0)*1024 + k0 + scol*8];
    ushort8 b0 = *(const ushort8*)&Bt[(size_t)(n0 + srow0)*1024 + k0 + scol*8];
    ushort8 a1 = *(const ushort8*)&A [(size_t)(m0 + srow1)*1024 + k0 + scol*8];
    ushort8 b1 = *(const ushort8*)&Bt[(size_t)(n0 + srow1)*1024 + k0 + scol*8];
    __syncthreads();
    *(ushort8*)&As[srow0*32 + scol*8] = a0;
    *(ushort8*)&Bs[srow0*32 + scol*8] = b0;
    *(ushort8*)&As[srow1*32 + scol*8] = a1;
    *(ushort8*)&Bs[srow1*32 + scol*8] = b1;
    __syncthreads();
    short8 af[4], bfr[4];
    #pragma unroll
    for (int i = 0; i < 4; ++i) af[i]  = lds8(&As[(wm*64 + i*16 + l15)*32 + quad*8]);
    #pragma unroll
    for (int j = 0; j < 4; ++j) bfr[j] = lds8(&Bs[(wn*64 + j*16 + l15)*32 + quad*8]);
    #pragma unroll
    for (int i = 0; i < 4; ++i)
      #pragma unroll
      for (int j = 0; j < 4; ++j)
        acc[i][j] = MFMA(af[i], bfr[j], acc[i][j]);
  }
  const int q4 = quad*4;
  #pragma unroll
  for (int i = 0; i < 4; ++i)
    #pragma unroll
    for (int j = 0; j < 4; ++j)
      #pragma unroll
      for (int r = 0; r < 4; ++r)
        C[(size_t)(m0 + wm*64 + i*16 + q4 + r)*ldc + n0 + wn*64 + j*16 + l15]
          = f2bf(acc[i][j][r] * ascale);
}

// ---------------------------------------------------------------------------
// NT GEMM bf16 -> f32 C: C[M][1024] = A[M][1024] @ Bt[1024][1024]^T
// ---------------------------------------------------------------------------
__global__ __launch_bounds__(256) void gemm_nt_f32(
    const u16* __restrict__ A, const u16* __restrict__ Bt, float* __restrict__ C)
{
  const int tid = threadIdx.x;
  const int lane = tid & 63, wave = tid >> 6;
  const int wm = wave >> 1, wn = wave & 1;
  const int l15 = lane & 15, quad = lane >> 4;
  const int m0 = blockIdx.y * 128, n0 = blockIdx.x * 128;
  __shared__ u16 As[128*32], Bs[128*32];
  f32x4 acc[4][4] = {};
  const int srow0 = tid >> 2, scol = tid & 3;
  const int srow1 = (tid + 256) >> 2;
  for (int k0 = 0; k0 < 1024; k0 += 32) {
    ushort8 a0 = *(const ushort8*)&A [(size_t)(m0 + srow0)*1024 + k0 + scol*8];
    ushort8 b0 = *(const ushort8*)&Bt[(size_t)(n0 + srow0)*1024 + k0 + scol*8];
    ushort8 a1 = *(const ushort8*)&A [(size_t)(m0 + srow1)*1024 + k0 + scol*8];
    ushort8 b1 = *(const ushort8*)&Bt[(size_t)(n0 + srow1)*1024 + k0 + scol*8];
    __syncthreads();
    *(ushort8*)&As[srow0*32 + scol*8] = a0;
    *(ushort8*)&Bs[srow0*32 + scol*8] = b0;
    *(ushort8*)&As[srow1*32 + scol*8] = a1;
    *(ushort8*)&Bs[srow1*32 + scol*8] = b1;
    __syncthreads();
    short8 af[4], bfr[4];
    #pragma unroll
    for (int i = 0; i < 4; ++i) af[i]  = lds8(&As[(wm*64 + i*16 + l15)*32 + quad*8]);
    #pragma unroll
    for (int j = 0; j < 4; ++j) bfr[j] = lds8(&Bs[(wn*64 + j*16 + l15)*32 + quad*8]);
    #pragma unroll
    for (int i = 0; i < 4; ++i)
      #pragma unroll
      for (int j = 0; j < 4; ++j)
        acc[i][j] = MFMA(af[i], bfr[j], acc[i][j]);
  }
  const int q4 = quad*4;
  #pragma unroll
  for (int i = 0; i < 4; ++i)
    #pragma unroll
    for (int j = 0; j < 4; ++j)
      #pragma unroll
      for (int r = 0; r < 4; ++r)
        C[(size_t)(m0 + wm*64 + i*16 + q4 + r)*1024 + n0 + wn*64 + j*16 + l15]
          = acc[i][j][r];
}

// ---------------------------------------------------------------------------
// NN GEMM bf16 with fp32 accumulate-into-C:
// C[M][1024] += A[M][2048] @ B[2048][1024]   (per-batch via blockIdx.z)
// ---------------------------------------------------------------------------
__global__ __launch_bounds__(256) void gemm_nn_add(
    const u16* __restrict__ A0, const u16* __restrict__ B0, float* __restrict__ C0)
{
  const int tid = threadIdx.x;
  const int lane = tid & 63, wave = tid >> 6;
  const int wm = wave >> 1, wn = wave & 1;
  const int l15 = lane & 15, quad = lane >> 4;
  const int m0 = blockIdx.y * 128, n0 = blockIdx.x * 128;
  const u16* A = A0 + (size_t)blockIdx.z * Nx * Nx;
  const u16* B = B0 + (size_t)blockIdx.z * Nx * Dx;
  float*     C = C0 + (size_t)blockIdx.z * Nx * Dx;
  __shared__ u16 As[128*32];
  __shared__ u16 Bs[128*40];
  f32x4 acc[4][4] = {};
  const int srow0 = tid >> 2, scol = tid & 3;
  const int srow1 = (tid + 256) >> 2;
  const int kp  = tid >> 4;
  const int nc8 = (tid & 15) * 8;
  for (int k0 = 0; k0 < Nx; k0 += 32) {
    ushort8 a0 = *(const ushort8*)&A[(size_t)(m0 + srow0)*Nx + k0 + scol*8];
    ushort8 a1 = *(const ushort8*)&A[(size_t)(m0 + srow1)*Nx + k0 + scol*8];
    ushort8 b0 = *(const ushort8*)&B[(size_t)(k0 + 2*kp    )*Dx + n0 + nc8];
    ushort8 b1 = *(const ushort8*)&B[(size_t)(k0 + 2*kp + 1)*Dx + n0 + nc8];
    __syncthreads();
    *(ushort8*)&As[srow0*32 + scol*8] = a0;
    *(ushort8*)&As[srow1*32 + scol*8] = a1;
    #pragma unroll
    for (int j = 0; j < 8; ++j){
      int n = nc8 + j;
      int slot = kp ^ (((n >> 3) & 3) << 2);
      *(u32*)&Bs[n*40 + slot*2] = (u32)(u16)b0[j] | ((u32)(u16)b1[j] << 16);
    }
    __syncthreads();
    short8 af[4], bfr[4];
    #pragma unroll
    for (int i = 0; i < 4; ++i) af[i] = lds8(&As[(wm*64 + i*16 + l15)*32 + quad*8]);
    #pragma unroll
    for (int j = 0; j < 4; ++j){
      int n = wn*64 + j*16 + l15;
      int q2 = quad ^ ((n >> 3) & 3);
      bfr[j] = lds8(&Bs[n*40 + q2*8]);
    }
    #pragma unroll
    for (int i = 0; i < 4; ++i)
      #pragma unroll
      for (int j = 0; j < 4; ++j)
        acc[i][j] = MFMA(af[i], bfr[j], acc[i][j]);
  }
  const int q4 = quad*4;
  #pragma unroll
  for (int i = 0; i < 4; ++i)
    #pragma unroll
    for (int j = 0; j < 4; ++j)
      #pragma unroll
      for (int r = 0; r < 4; ++r){
        size_t idx = (size_t)(m0 + wm*64 + i*16 + q4 + r)*Dx + n0 + wn*64 + j*16 + l15;
        C[idx] += acc[i][j][r];
      }
}

// ---------------------------------------------------------------------------
// diag_k: Dbuf[b][row] = x[b][row] . x[b][row]  (exact fp32)
// ---------------------------------------------------------------------------
__global__ __launch_bounds__(256) void diag_k(const u16* __restrict__ x,
                                              float* __restrict__ Dbuf)
{
  const int b = blockIdx.y;
  const int row = blockIdx.x*64 + (threadIdx.x >> 2);
  const int part = threadIdx.x & 3;
  float s = 0.f;
  #pragma unroll
  for (int i = 0; i < 32; ++i) {
    short8 v = *(const short8*)&x[(size_t)b*Nx*Dx + (size_t)row*Dx + part*256 + i*8];
    #pragma unroll
    for (int k = 0; k < 8; ++k){ float f = bf2f((u16)v[k]); s += f*f; }
  }
  s += __shfl_xor(s, 1); s += __shfl_xor(s, 2);
  if (part == 0) Dbuf[b*2048 + row] = s;
}

// ---------------------------------------------------------------------------
// attnA: no-max flash, split-K x2, K/V LDS-shared. grid (32,32,2) x 256.
// One barrier/iter; double-buffered K/V tiles; tile mt+2 prefetched mid-body.
// ---------------------------------------------------------------------------
__global__ __launch_bounds__(256, 4) void attnA(
    const u16* __restrict__ Qbuf, const u16* __restrict__ K16,
    const u16* __restrict__ wkwq,
    const u16* __restrict__ Vb0, const u16* __restrict__ Vb1a,
    const u16* __restrict__ Vb1b, const u16* __restrict__ xxt,
    const float* __restrict__ Dbuf,
    u16* __restrict__ O1, u16* __restrict__ O2,
    float* __restrict__ L1, float* __restrict__ L2)
{
  __shared__ __align__(16) u16 Ks[2][32*66];   // [key 0..31][d 0..63], row pad 66
  __shared__ __align__(16) u16 Vs[2][64*34];   // [d 0..63][key 0..31], row pad 34
  __shared__ __align__(16) u16 prt[4*640];     // per-wave P transpose
  const int tid = threadIdx.x;
  const int lane = tid & 63, w = tid >> 6;
  const int l15 = lane & 15, quad = lane >> 4, q4 = quad*4;
  const int hb = blockIdx.y;
  const int c = hb & 15, b = hb >> 4;
  const int qt = blockIdx.x;
  const int sp = blockIdx.z;
  const int kt0 = sp * 32;
  const size_t xbase  = (size_t)b * Nx * Dx;
  const size_t xxbase = (size_t)b * Nx * Nx;
  const int row0 = qt*64 + w*16;

  u16* prtw = prt + w*640;
  u16*  Osp = sp ? O2 : O1;
  float* Lsp = sp ? L2 : L1;
  const int mtd = (row0 >> 5) - kt0;           // only this iter can hit diagonal

  short8 qf[2];
  #pragma unroll
  for (int s = 0; s < 2; ++s)
    qf[s] = *(const short8*)&Qbuf[(size_t)(b*2048 + row0 + l15)*1024 + c*64 + s*32 + quad*8];
  float dv[4];
  #pragma unroll
  for (int r = 0; r < 4; ++r) dv[r] = Dbuf[b*2048 + row0 + q4 + r];
  const float wkh = bf2f(wkwq[c]) * L2E;

  const u16* vbp; int dof;
  if (b == 0){ vbp = Vb0; dof = 0; }
  else if (c < 8){ vbp = Vb1a; dof = 0; }
  else { vbp = Vb1b; dof = 512; }

  // staging maps: 256 threads cover K tile [32][64] and V tile [64][32]
  const int krow = tid >> 3, kc8 = (tid & 7) * 8;
  const int vrow = tid >> 2, vc8 = (tid & 3) * 8;
  const u16* pkg = K16 + xbase + (size_t)(kt0*32 + krow)*Dx + c*64 + kc8;
  const u16* pvg = vbp + (size_t)(c*64 - dof + vrow)*Nx + kt0*32 + vc8;

  f32x4 O[4] = {};
  float lrun[4] = {0.f, 0.f, 0.f, 0.f};
  const u16* pxx = xxt + xxbase + (size_t)(row0 + q4)*Nx + kt0*32 + l15;

  // prologue: tile0 -> LDS[0]; tile1 -> regs
  ushort8 kst = *(const ushort8*)&pkg[0];
  ushort8 vst = *(const ushort8*)&pvg[0];
  *(ushort8*)&Ks[0][krow*66 + kc8] = kst;
  *(ushort8*)&Vs[0][vrow*34 + vc8] = vst;
  kst = *(const ushort8*)&pkg[(size_t)32*Dx];
  vst = *(const ushort8*)&pvg[32];
  __syncthreads();

  #pragma unroll 1
  for (int mt = 0; mt < 32; ++mt) {
    const int cur = mt & 1, nxt = cur ^ 1;
    // frag reads from LDS[cur]
    short8 kf[2][2], vf[4];
    #pragma unroll
    for (int s = 0; s < 2; ++s)
      #pragma unroll
      for (int k2 = 0; k2 < 2; ++k2)
        kf[s][k2] = lds8(&Ks[cur][(s*16 + l15)*66 + k2*32 + quad*8]);
    #pragma unroll
    for (int dt = 0; dt < 4; ++dt)
      vf[dt] = lds8(&Vs[cur][(dt*16 + l15)*34 + quad*8]);
    // xb bias values (global, per-wave)
    float xb[2][4];
    #pragma unroll
    for (int s = 0; s < 2; ++s)
      #pragma unroll
      for (int r = 0; r < 4; ++r)
        xb[s][r] = bf2f(pxx[r*Nx + s*16]);
    // store staged tile mt+1 -> LDS[nxt] (waits on loads issued last iter)
    if (mt < 31) {
      *(ushort8*)&Ks[nxt][krow*66 + kc8] = kst;
      *(ushort8*)&Vs[nxt][vrow*34 + vc8] = vst;
    }
    // issue loads for tile mt+2
    if (mt < 30) {
      kst = *(const ushort8*)&pkg[(size_t)(mt+2)*32*Dx];
      vst = *(const ushort8*)&pvg[(size_t)(mt+2)*32];
    }
    // compute
    f32x4 t2[2];
    #pragma unroll
    for (int s = 0; s < 2; ++s){
      f32x4 t = {};
      t = MFMA(qf[0], kf[s][0], t);
      t = MFMA(qf[1], kf[s][1], t);
      t2[s] = t;
    }
    if (mt == mtd) {                          // wave-uniform branch
      const int kb = (kt0 + mt)*32 + l15;
      #pragma unroll
      for (int s = 0; s < 2; ++s)
        #pragma unroll
        for (int r = 0; r < 4; ++r){
          const int ng = row0 + q4 + r;
          float bias = (kb + s*16 == ng) ? dv[r] : xb[s][r];
          float p = exp2f(t2[s][r] + wkh*bias);
          lrun[r] += p;
          prtw[(q4+r)*40 + s*16 + l15] = f2bf(p);
        }
    } else {
      #pragma unroll
      for (int s = 0; s < 2; ++s)
        #pragma unroll
        for (int r = 0; r < 4; ++r){
          float p = exp2f(t2[s][r] + wkh*xb[s][r]);
          lrun[r] += p;
          prtw[(q4+r)*40 + s*16 + l15] = f2bf(p);
        }
    }
    short8 pf = lds8(&prtw[l15*40 + quad*8]);
    #pragma unroll
    for (int dt = 0; dt < 4; ++dt) O[dt] = MFMA(pf, vf[dt], O[dt]);
    pxx += 32;
    __syncthreads();                          // orders LDS[nxt] stores & prt reuse
  }

  // cross-lane l sum (within the 16-lane group owning these rows)
  #pragma unroll
  for (int r = 0; r < 4; ++r){
    float l = lrun[r];
    l += __shfl_xor(l, 1); l += __shfl_xor(l, 2);
    l += __shfl_xor(l, 4); l += __shfl_xor(l, 8);
    lrun[r] = l;
  }
  #pragma unroll
  for (int dt = 0; dt < 4; ++dt)
    #pragma unroll
    for (int r = 0; r < 4; ++r)
      Osp[(size_t)(b*2048 + row0 + q4 + r)*1024 + c*64 + dt*16 + l15]
        = f2bf(O[dt][r]);
  if (l15 == 0){
    #pragma unroll
    for (int r = 0; r < 4; ++r)
      Lsp[(size_t)(b*2048 + row0 + q4 + r)*16 + c] = lrun[r];
  }
}

// ---------------------------------------------------------------------------
// attnM: merge splits. Obuf = (O1+O2) * il,  il = 1/(l1+l2); emit Sil.
// ---------------------------------------------------------------------------
__global__ __launch_bounds__(128) void attnM(
    const u16* __restrict__ O1, const u16* __restrict__ O2,
    const float* __restrict__ L1, const float* __restrict__ L2,
    u16* __restrict__ Obuf, float* __restrict__ Sil)
{
  const int row = blockIdx.x;
  const int t = threadIdx.x;
  const int h = t >> 3;
  const float il = 1.0f / fmaxf(L1[(size_t)row*16 + h] + L2[(size_t)row*16 + h], 1e-30f);
  short8 a = *(const short8*)&O1[(size_t)row*1024 + t*8];
  short8 b = *(const short8*)&O2[(size_t)row*1024 + t*8];
  ushort8 o;
  #pragma unroll
  for (int j = 0; j < 8; ++j)
    o[j] = f2bf((bf2f((u16)a[j]) + bf2f((u16)b[j])) * il);
  *(ushort8*)&Obuf[(size_t)row*1024 + t*8] = o;
  if ((t & 7) == 0) Sil[(size_t)row*16 + h] = il;
}

// ---------------------------------------------------------------------------
// attnB: PSA[b][q][k] = sum_h wvh * il_h * exp2(sv_h), 64x64 tiles.
// ---------------------------------------------------------------------------
__global__ __launch_bounds__(256, 4) void attnB(
    const u16* __restrict__ Qbuf, const u16* __restrict__ K16,
    const u16* __restrict__ wkwq, const u16* __restrict__ wvwo,
    const u16* __restrict__ xxt, const float* __restrict__ Sil,
    const float* __restrict__ Dbuf, u16* __restrict__ PSA)
{
  __shared__ float sst[1024];                // [64 rows][16 h] il
  const int tid = threadIdx.x;
  const int lane = tid & 63, w = tid >> 6;
  const int l15 = lane & 15, quad = lane >> 4, q4 = quad*4;
  const int kt = blockIdx.x, qt = blockIdx.y, b = blockIdx.z;
  const size_t xbase  = (size_t)b * Nx * Dx;
  const size_t xxbase = (size_t)b * Nx * Nx;

  {
    const float* src = Sil + ((size_t)b*2048 + qt*64)*16;
    for (int i = tid; i < 1024; i += 256) sst[i] = src[i];
  }
  __syncthreads();

  const int rloc = w*16 + q4;
  float xbv[4][4];
  #pragma unroll
  for (int ks = 0; ks < 4; ++ks)
    #pragma unroll
    for (int r = 0; r < 4; ++r){
      int gr = qt*64 + rloc + r;
      int gc = kt*64 + ks*16 + l15;
      float v = bf2f(xxt[xxbase + (size_t)gr*Nx + gc]);
      if (gr == gc) v = Dbuf[b*2048 + gr];
      xbv[ks][r] = v;
    }

  f32x4 psa_[4] = {};
  #pragma unroll 2
  for (int h = 0; h < 16; ++h){
    const float wkh = bf2f(wkwq[h]) * L2E;
    const float wvh = bf2f(wvwo[h]);
    short8 qf[2];
    #pragma unroll
    for (int s = 0; s < 2; ++s)
      qf[s] = *(const short8*)&Qbuf[(size_t)(b*2048 + qt*64 + w*16 + l15)*1024 + h*64 + s*32 + quad*8];
    short8 kf[4][2];
    #pragma unroll
    for (int ks = 0; ks < 4; ++ks)
      #pragma unroll
      for (int k2 = 0; k2 < 2; ++k2)
        kf[ks][k2] = *(const short8*)&K16[xbase + (size_t)(kt*64 + ks*16 + l15)*Dx + h*64 + k2*32 + quad*8];
    #pragma unroll
    for (int ks = 0; ks < 4; ++ks){
      f32x4 t = {};
      t = MFMA(qf[0], kf[ks][0], t);
      t = MFMA(qf[1], kf[ks][1], t);
      #pragma unroll
      for (int r = 0; r < 4; ++r){
        float ilw = sst[(rloc + r)*16 + h] * wvh;
        psa_[ks][r] += exp2f(t[r] + wkh*xbv[ks][r]) * ilw;
      }
    }
  }
  #pragma unroll
  for (int ks = 0; ks < 4; ++ks)
    #pragma unroll
    for (int r = 0; r < 4; ++r)
      PSA[(size_t)(b*2048 + qt*64 + rloc + r)*Nx + kt*64 + ks*16 + l15]
        = f2bf(psa_[ks][r]);
}

// ---------------------------------------------------------------------------
// attn2 (v13 path, verified) — fallback if ws in [16MB, NEED)
// ---------------------------------------------------------------------------
#define B_PRT 0
#define B_PSP 20480
#define B_DG  61440
#define B_SZ  86016

__global__ __launch_bounds__(1024)
__attribute__((amdgpu_waves_per_eu(4, 4)))
void attn2(
    const u16* __restrict__ x, const u16* __restrict__ wq,
    const u16* __restrict__ wo, const u16* __restrict__ wkwq,
    const u16* __restrict__ wvwo, const u16* __restrict__ K16,
    const u16* __restrict__ Vb0, const u16* __restrict__ Vb1a,
    const u16* __restrict__ Vb1b, u16* __restrict__ PSA,
    float* out)
{
  __shared__ __align__(16) u8 AR[B_SZ];
  const int tid = threadIdx.x;
  const int lane = tid & 63, c = tid >> 6;
  const int l15 = lane & 15, quad = lane >> 4, q4 = quad*4;
  int bb = blockIdx.x; bb = (bb & 7)*32 + (bb >> 3);
  const int b = bb >> 7, n0 = (bb & 127) * 16;
  const size_t xbase = (size_t)b * Nx * Dx;
  const u16* xxt = (const u16*)out;
  const size_t xxbase = (size_t)b * Nx * Nx;
  u16* psag = PSA + (size_t)b * Nx * Nx;

  u16*   prt = (u16*)(AR + B_PRT);
  u16*   psp = (u16*)(AR + B_PSP);
  float* dgv = (float*)(AR + B_DG);
  u16*   qrt = (u16*)(AR + 0) + c*(16*72);

  {
    f32x4 qacc[4] = {};
    #pragma unroll 1
    for (int kc = 0; kc < 32; ++kc) {
      short8 af = *(const short8*)&x[xbase + (size_t)(n0 + l15)*Dx + kc*32 + quad*8];
      #pragma unroll
      for (int j = 0; j < 4; ++j) {
        short8 bf = *(const short8*)&wq[(size_t)(c*64 + j*16 + l15)*Dx + kc*32 + quad*8];
        qacc[j] = MFMA(af, bf, qacc[j]);
      }
    }
    const float qs = SCALEx * L2E;
    #pragma unroll
    for (int j = 0; j < 4; ++j)
      #pragma unroll
      for (int r = 0; r < 4; ++r)
        qrt[(q4+r)*72 + j*16 + l15] = f2bf(qacc[j][r] * qs);
  }
  {
    float s = 0.f;
    #pragma unroll
    for (int p = 0; p < 2; ++p) {
      short8 v = *(const short8*)&x[xbase + (size_t)(n0+c)*Dx + p*512 + lane*8];
      #pragma unroll
      for (int i = 0; i < 8; ++i){ float f = bf2f((u16)v[i]); s += f*f; }
    }
    #pragma unroll
    for (int o = 1; o < 64; o <<= 1) s += __shfl_xor(s, o);
    if (lane == 0) dgv[c] = s;
  }
  short8 qf[2];
  #pragma unroll
  for (int s = 0; s < 2; ++s) qf[s] = lds8(&qrt[l15*72 + s*32 + quad*8]);
  __syncthreads();
  float dv[4];
  #pragma unroll
  for (int r = 0; r < 4; ++r) dv[r] = dgv[q4+r];
  __syncthreads();

  const float wkh = bf2f(wkwq[c]) * L2E;
  const float wvh = bf2f(wvwo[c]);

  float mrun[4], lrun[4];
  #pragma unroll
  for (int r = 0; r < 4; ++r){ mrun[r] = -1e30f; lrun[r] = 0.f; }

  const u16* pk  = K16 + xbase + (size_t)l15*Dx + c*64;
  const u16* pxx = xxt + xxbase + (size_t)(n0+q4)*Nx + l15;

  #pragma unroll 2
  for (int mt = 0; mt < 64; ++mt) {
    float xb[2][4];
    #pragma unroll
    for (int s = 0; s < 2; ++s)
      #pragma unroll
      for (int r = 0; r < 4; ++r)
        xb[s][r] = bf2f(pxx[r*Nx + s*16]);
    short8 kf[2][2];
    #pragma unroll
    for (int s = 0; s < 2; ++s)
      #pragma unroll
      for (int k2 = 0; k2 < 2; ++k2)
        kf[s][k2] = *(const short8*)&pk[s*16*Dx + k2*32 + quad*8];
    f32x4 t2[2];
    #pragma unroll
    for (int s = 0; s < 2; ++s){
      f32x4 t = {};
      t = MFMA(qf[0], kf[s][0], t);
      t = MFMA(qf[1], kf[s][1], t);
      t2[s] = t;
    }
    const int kb = mt*32 + l15;
    #pragma unroll
    for (int r = 0; r < 4; ++r){
      const int ng = n0 + q4 + r;
      float b0 = (kb      == ng) ? dv[r] : xb[0][r];
      float b1 = (kb + 16 == ng) ? dv[r] : xb[1][r];
      float sv0 = t2[0][r] + wkh*b0;
      float sv1 = t2[1][r] + wkh*b1;
      float m2 = fmaxf(sv0, sv1);
      float mn = fmaxf(mrun[r], m2);
      lrun[r] = lrun[r]*exp2f(mrun[r]-mn) + exp2f(sv0-mn) + exp2f(sv1-mn);
      mrun[r] = mn;
    }
    pk += 32*Dx; pxx += 32;
  }
  float ms[4], il[4];
  #pragma unroll
  for (int r = 0; r < 4; ++r){
    float mr = mrun[r];
    #pragma unroll
    for (int o = 1; o < 16; o <<= 1) mr = fmaxf(mr, __shfl_xor(mr, o));
    float ls = lrun[r]*exp2f(mrun[r]-mr);
    #pragma unroll
    for (int o = 1; o < 16; o <<= 1) ls += __shfl_xor(ls, o);
    ms[r] = mr; il[r] = 1.0f/fmaxf(ls, 1e-30f);
  }

  f32x4 O[4] = {};
  const u16* vbp; int voff;
  if (b == 0){ vbp = Vb0; voff = 0; }
  else if (c < 8){ vbp = Vb1a; voff = 0; }
  else { vbp = Vb1b; voff = 512; }
  const u16* pv = vbp + (size_t)(c*64 - voff + l15)*Nx;
  pk  = K16 + xbase + (size_t)l15*Dx + c*64;
  pxx = xxt + xxbase + (size_t)(n0+q4)*Nx + l15;

  #pragma unroll 1
  for (int mt = 0; mt < 64; ++mt) {
    float xb[2][4];
    #pragma unroll
    for (int s = 0; s < 2; ++s)
      #pragma unroll
      for (int r = 0; r < 4; ++r)
        xb[s][r] = bf2f(pxx[r*Nx + s*16]);
    short8 kf[2][2];
    #pragma unroll
    for (int s = 0; s < 2; ++s)
      #pragma unroll
      for (int k2 = 0; k2 < 2; ++k2)
        kf[s][k2] = *(const short8*)&pk[s*16*Dx + k2*32 + quad*8];
    short8 vf[4];
    #pragma unroll
    for (int dt = 0; dt < 4; ++dt)
      vf[dt] = *(const short8*)&pv[dt*16*Nx + quad*8];
    f32x4 t2[2];
    #pragma unroll
    for (int s = 0; s < 2; ++s){
      f32x4 t = {};
      t = MFMA(qf[0], kf[s][0], t);
      t = MFMA(qf[1], kf[s][1], t);
      t2[s] = t;
    }
    const int kb = mt*32 + l15;
    u16* pspw = psp + (mt & 1)*10240;
    #pragma unroll
    for (int s = 0; s < 2; ++s)
      #pragma unroll
      for (int r = 0; r < 4; ++r){
        const int ng = n0 + q4 + r;
        float bias = (kb + s*16 == ng) ? dv[r] : xb[s][r];
        float sv = t2[s][r] + wkh*bias;
        float p = exp2f(fminf(sv - ms[r], 0.f)) * il[r];
        prt[c*640 + (q4+r)*40 + s*16 + l15] = f2bf(p);
        pspw[c*640 + (q4+r)*40 + s*16 + l15] = f2bf(wvh * p);
      }
    short8 pf = lds8(&prt[c*640 + l15*40 + quad*8]);
    #pragma unroll
    for (int dt = 0; dt < 4; ++dt) O[dt] = MFMA(pf, vf[dt], O[dt]);
    __syncthreads();
    if (tid < 512){
      const int qq = tid >> 5, mm = tid & 31;
      float v = 0.f;
      #pragma unroll
      for (int w = 0; w < 16; ++w) v += bf2f(pspw[w*640 + qq*40 + mm]);
      psag[(size_t)(n0 + qq)*Nx + mt*32 + mm] = f2bf(v);
    }
    pk += 32*Dx; pxx += 32; pv += 32;
  }

  __syncthreads();
  u16* ol = (u16*)(AR + 0);
  #pragma unroll
  for (int dt = 0; dt < 4; ++dt)
    #pragma unroll
    for (int r = 0; r < 4; ++r)
      ol[(q4+r)*1040 + c*64 + dt*16 + l15] = f2bf(O[dt][r]);
  __syncthreads();
  f32x4 Uo[4] = {};
  #pragma unroll 1
  for (int kc = 0; kc < 32; ++kc){
    short8 af = lds8(&ol[l15*1040 + kc*32 + quad*8]);
    #pragma unroll
    for (int ct = 0; ct < 4; ++ct){
      short8 bw = *(const short8*)&wo[(size_t)(c*64 + ct*16 + l15)*Dx + kc*32 + quad*8];
      Uo[ct] = MFMA(af, bw, Uo[ct]);
    }
  }
  #pragma unroll
  for (int ct = 0; ct < 4; ++ct)
    #pragma unroll
    for (int r = 0; r < 4; ++r)
      out[xbase + (size_t)(n0+q4+r)*Dx + c*64 + ct*16 + l15] = Uo[ct][r];
}

// ---------------------------------------------------------------------------
extern "C" void kernel_launch(void* const* d_in, const int* in_sizes, int n_in,
                              void* d_out, int out_size, void* d_ws, size_t ws_size,
                              hipStream_t stream) {
  u16* x16   = (u16*)d_in[0];
  u16* K16   = x16 + 4u*1024u*1024u;
  u16* wqk16 = (u16*)d_in[1];
  u16* Vb0   = wqk16 + 2u*1024u*1024u;
  u16* wv16  = (u16*)d_in[2];
  u16* Vb1a  = wv16 + 1024u*1024u;
  u16* wo16  = (u16*)d_in[3];
  u16* Vb1b  = wo16 + 1024u*1024u;
  float* outF = (float*)d_out;
  u16* S = (u16*)d_out;

  const float loW = 0.000244140625f, hiW = 0.25f;
  conv_w<<<dim3(512), 256, 0, stream>>>(d_in[0], S, 4*1024*1024, 512, 0.00390625f, 16.0f);
  copyb <<<dim3(512), 256, 0, stream>>>(S, x16, 4*1024*1024);
  conv_w<<<dim3(256), 256, 0, stream>>>(d_in[1], S, 2*1024*1024, 512, loW, hiW);
  copyb <<<dim3(256), 256, 0, stream>>>(S, wqk16, 2*1024*1024);
  conv_w<<<dim3(128), 256, 0, stream>>>(d_in[2], S, 1024*1024, 512, loW, hiW);
  copyb <<<dim3(128), 256, 0, stream>>>(S, wv16, 1024*1024);
  conv_w<<<dim3(128), 256, 0, stream>>>(d_in[3], S, 1024*1024, 512, loW, hiW);
  copyb <<<dim3(128), 256, 0, stream>>>(S, wo16, 1024*1024);
  conv_small<<<dim3(1), 64, 0, stream>>>((void*)d_in[4], 16, loW, hiW);
  conv_small<<<dim3(1), 64, 0, stream>>>((void*)d_in[5], 16, loW, hiW);

  // ws layout (bytes)
  const size_t OFF_PSA = 0;              // 16 MB
  const size_t OFF_Q   = 16777216;       //  8 MB
  const size_t OFF_OB  = 25165824;       //  8 MB (normalized O)
  const size_t OFF_O1  = 33554432;       //  8 MB
  const size_t OFF_O2  = 41943040;       //  8 MB
  const size_t OFF_L1  = 50331648;       // 256 KB
  const size_t OFF_L2  = 50593792;       // 256 KB
  const size_t OFF_SI  = 50855936;       // 256 KB
  const size_t OFF_D   = 51118080;       //  16 KB
  const size_t NEED    = 51134464;

  // K = x @ wk^T (both batches)
  gemm_bf16<<<dim3(8, 32), 256, 0, stream>>>(x16, wqk16 + 1024u*1024u, K16, 1024, 1.0f);
  // V^T = wv @ x^T
  gemm_bf16<<<dim3(16, 8), 256, 0, stream>>>(wv16, x16, Vb0, 2048, 1.0f);
  gemm_bf16<<<dim3(16, 4), 256, 0, stream>>>(wv16,              x16 + 2048u*1024u, Vb1a, 2048, 1.0f);
  gemm_bf16<<<dim3(16, 4), 256, 0, stream>>>(wv16 + 512u*1024u, x16 + 2048u*1024u, Vb1b, 2048, 1.0f);
  // XXT = x @ x^T (bf16) into d_out
  gemm_bf16<<<dim3(16, 16), 256, 0, stream>>>(x16,               x16,               (u16*)d_out,                  2048, 1.0f);
  gemm_bf16<<<dim3(16, 16), 256, 0, stream>>>(x16 + 2048u*1024u, x16 + 2048u*1024u, (u16*)d_out + 4u*1024u*1024u, 2048, 1.0f);

  if (d_ws != nullptr && ws_size >= NEED) {
    u8* ws = (u8*)d_ws;
    // Q = (x @ wq^T) * SCALE*log2e
    gemm_bf16<<<dim3(8, 32), 256, 0, stream>>>(x16, wqk16, (u16*)(ws + OFF_Q), 1024, SCALEx * L2E);
    diag_k<<<dim3(32, 2), 256, 0, stream>>>(x16, (float*)(ws + OFF_D));
    attnA<<<dim3(32, 32, 2), 256, 0, stream>>>(
        (const u16*)(ws + OFF_Q), K16, (const u16*)d_in[4],
        Vb0, Vb1a, Vb1b, (const u16*)d_out, (const float*)(ws + OFF_D),
        (u16*)(ws + OFF_O1), (u16*)(ws + OFF_O2),
        (float*)(ws + OFF_L1), (float*)(ws + OFF_L2));
    attnM<<<dim3(4096), 128, 0, stream>>>(
        (const u16*)(ws + OFF_O1), (const u16*)(ws + OFF_O2),
        (const float*)(ws + OFF_L1), (const float*)(ws + OFF_L2),
        (u16*)(ws + OFF_OB), (float*)(ws + OFF_SI));
    attnB<<<dim3(32, 32, 2), 256, 0, stream>>>(
        (const u16*)(ws + OFF_Q), K16, (const u16*)d_in[4], (const u16*)d_in[5],
        (const u16*)d_out, (const float*)(ws + OFF_SI), (const float*)(ws + OFF_D),
        (u16*)(ws + OFF_PSA));
    gemm_nt_f32<<<dim3(8, 32), 256, 0, stream>>>((const u16*)(ws + OFF_OB), wo16, outF);
    gemm_nn_add<<<dim3(8, 16, 2), 256, 0, stream>>>((const u16*)(ws + OFF_PSA), x16, outF);
  } else if (d_ws != nullptr && ws_size >= (size_t)2*2048*2048*2) {
    attn2<<<dim3(256), 1024, 0, stream>>>(x16, wqk16, wo16,
        (const u16*)d_in[4], (const u16*)d_in[5], K16, Vb0, Vb1a, Vb1b,
        (u16*)d_ws, outF);
    gemm_nn_add<<<dim3(8, 16, 2), 256, 0, stream>>>((const u16*)d_ws, x16, outF);
  }
}

// Round 11
// 916.741 us; speedup vs baseline: 1.0203x; 1.0203x over previous
//
// v18: revert v17's K/V LDS staging (regression: L2 absorbed the redundant
// gathers, FETCH unchanged, but the added barrier re-coupled waves and 3x'd
// bank conflicts -> 262->296). attnA = v16 loop + unroll 4 + prt QUAD-buffer
// ((mt&3)*640, removes the 2-deep WAR cap). attnB: head-split x2 (8 heads per
// block, grid z=4, halves -> PSH buffers) + addp merge kernel; gemm_nn_add
// unchanged. Everything else verbatim from harness-verified v16/v17.
#include <hip/hip_runtime.h>

typedef unsigned short u16;
typedef unsigned int   u32;
typedef unsigned char  u8;
typedef __attribute__((ext_vector_type(8))) short          short8;
typedef __attribute__((ext_vector_type(8))) unsigned short ushort8;
typedef __attribute__((ext_vector_type(4))) float          f32x4;

#define MFMA(a,b,c) __builtin_amdgcn_mfma_f32_16x16x32_bf16((a),(b),(c),0,0,0)
#define Nx 2048
#define Dx 1024
#define SCALEx 0.125f
#define L2E 1.4426950408889634f

__device__ __forceinline__ float bf2f(u16 u){ u32 x=((u32)u)<<16; return __builtin_bit_cast(float,x); }
__device__ __forceinline__ u16 f2bf(float f){ u32 u=__builtin_bit_cast(u32,f); u32 r=(u+0x7FFFu+((u>>16)&1u))>>16; return (u16)r; }
__device__ __forceinline__ short8 lds8(const u16* p){ return *(const short8*)p; }

// ---- dtype normalization (identity if already bf16) ----
__device__ int looks_bf16_dev(const u16* p, int nsamp, float lo, float hi){
  int cnt = 0;
  for (int i = 0; i < nsamp; ++i){
    float a = fabsf(bf2f(p[2*i]));
    if (a >= lo && a <= hi) cnt++;
  }
  return (2*cnt > nsamp) ? 1 : 0;
}

__global__ __launch_bounds__(256) void conv_w(const void* __restrict__ in, u16* __restrict__ S,
                                              int n, int nsamp, float lo, float hi){
  __shared__ int flag;
  if (threadIdx.x == 0) flag = looks_bf16_dev((const u16*)in, nsamp, lo, hi);
  __syncthreads();
  const int isbf = flag;
  int i = blockIdx.x*256 + threadIdx.x;
  int stride = gridDim.x*256;
  if (isbf){
    const u16* pu = (const u16*)in;
    for (; i < n; i += stride) S[i] = pu[i];
  } else {
    const float* pf = (const float*)in;
    for (; i < n; i += stride) S[i] = f2bf(pf[i]);
  }
}

__global__ __launch_bounds__(256) void copyb(const u16* __restrict__ S, u16* __restrict__ dst, int n){
  int i = blockIdx.x*256 + threadIdx.x;
  int stride = gridDim.x*256;
  for (; i < n; i += stride) dst[i] = S[i];
}

__global__ void conv_small(void* buf, int n, float lo, float hi){
  __shared__ float tmp[64];
  __shared__ int flag;
  int t = threadIdx.x;
  if (t == 0) flag = looks_bf16_dev((const u16*)buf, n/2, lo, hi);
  __syncthreads();
  if (t < n) tmp[t] = flag ? bf2f(((const u16*)buf)[t]) : ((const float*)buf)[t];
  __syncthreads();
  if (t < n) ((u16*)buf)[t] = f2bf(tmp[t]);
}

// ---------------------------------------------------------------------------
// NT GEMM bf16: C[M][ldc] = ascale * (A[M][1024] @ Bt[N][1024]^T)
// ---------------------------------------------------------------------------
__global__ __launch_bounds__(256) void gemm_bf16(
    const u16* __restrict__ A, const u16* __restrict__ Bt, u16* __restrict__ C,
    int ldc, float ascale)
{
  const int tid = threadIdx.x;
  const int lane = tid & 63, wave = tid >> 6;
  const int wm = wave >> 1, wn = wave & 1;
  const int l15 = lane & 15, quad = lane >> 4;
  const int m0 = blockIdx.y * 128, n0 = blockIdx.x * 128;
  __shared__ u16 As[128*32], Bs[128*32];
  f32x4 acc[4][4] = {};
  const int srow0 = tid >> 2, scol = tid & 3;
  const int srow1 = (tid + 256) >> 2;
  for (int k0 = 0; k0 < 1024; k0 += 32) {
    ushort8 a0 = *(const ushort8*)&A [(size_t)(m0 + srow0)*1024 + k0 + scol*8];
    ushort8 b0 = *(const ushort8*)&Bt[(size_t)(n0 + srow0)*1024 + k0 + scol*8];
    ushort8 a1 = *(const ushort8*)&A [(size_t)(m0 + srow1)*1024 + k0 + scol*8];
    ushort8 b1 = *(const ushort8*)&Bt[(size_t)(n0 + srow1)*1024 + k0 + scol*8];
    __syncthreads();
    *(ushort8*)&As[srow0*32 + scol*8] = a0;
    *(ushort8*)&Bs[srow0*32 + scol*8] = b0;
    *(ushort8*)&As[srow1*32 + scol*8] = a1;
    *(ushort8*)&Bs[srow1*32 + scol*8] = b1;
    __syncthreads();
    short8 af[4], bfr[4];
    #pragma unroll
    for (int i = 0; i < 4; ++i) af[i]  = lds8(&As[(wm*64 + i*16 + l15)*32 + quad*8]);
    #pragma unroll
    for (int j = 0; j < 4; ++j) bfr[j] = lds8(&Bs[(wn*64 + j*16 + l15)*32 + quad*8]);
    #pragma unroll
    for (int i = 0; i < 4; ++i)
      #pragma unroll
      for (int j = 0; j < 4; ++j)
        acc[i][j] = MFMA(af[i], bfr[j], acc[i][j]);
  }
  const int q4 = quad*4;
  #pragma unroll
  for (int i = 0; i < 4; ++i)
    #pragma unroll
    for (int j = 0; j < 4; ++j)
      #pragma unroll
      for (int r = 0; r < 4; ++r)
        C[(size_t)(m0 + wm*64 + i*16 + q4 + r)*ldc + n0 + wn*64 + j*16 + l15]
          = f2bf(acc[i][j][r] * ascale);
}

// ---------------------------------------------------------------------------
// NT GEMM bf16 -> f32 C: C[M][1024] = A[M][1024] @ Bt[1024][1024]^T
// ---------------------------------------------------------------------------
__global__ __launch_bounds__(256) void gemm_nt_f32(
    const u16* __restrict__ A, const u16* __restrict__ Bt, float* __restrict__ C)
{
  const int tid = threadIdx.x;
  const int lane = tid & 63, wave = tid >> 6;
  const int wm = wave >> 1, wn = wave & 1;
  const int l15 = lane & 15, quad = lane >> 4;
  const int m0 = blockIdx.y * 128, n0 = blockIdx.x * 128;
  __shared__ u16 As[128*32], Bs[128*32];
  f32x4 acc[4][4] = {};
  const int srow0 = tid >> 2, scol = tid & 3;
  const int srow1 = (tid + 256) >> 2;
  for (int k0 = 0; k0 < 1024; k0 += 32) {
    ushort8 a0 = *(const ushort8*)&A [(size_t)(m0 + srow0)*1024 + k0 + scol*8];
    ushort8 b0 = *(const ushort8*)&Bt[(size_t)(n0 + srow0)*1024 + k0 + scol*8];
    ushort8 a1 = *(const ushort8*)&A [(size_t)(m0 + srow1)*1024 + k0 + scol*8];
    ushort8 b1 = *(const ushort8*)&Bt[(size_t)(n0 + srow1)*1024 + k0 + scol*8];
    __syncthreads();
    *(ushort8*)&As[srow0*32 + scol*8] = a0;
    *(ushort8*)&Bs[srow0*32 + scol*8] = b0;
    *(ushort8*)&As[srow1*32 + scol*8] = a1;
    *(ushort8*)&Bs[srow1*32 + scol*8] = b1;
    __syncthreads();
    short8 af[4], bfr[4];
    #pragma unroll
    for (int i = 0; i < 4; ++i) af[i]  = lds8(&As[(wm*64 + i*16 + l15)*32 + quad*8]);
    #pragma unroll
    for (int j = 0; j < 4; ++j) bfr[j] = lds8(&Bs[(wn*64 + j*16 + l15)*32 + quad*8]);
    #pragma unroll
    for (int i = 0; i < 4; ++i)
      #pragma unroll
      for (int j = 0; j < 4; ++j)
        acc[i][j] = MFMA(af[i], bfr[j], acc[i][j]);
  }
  const int q4 = quad*4;
  #pragma unroll
  for (int i = 0; i < 4; ++i)
    #pragma unroll
    for (int j = 0; j < 4; ++j)
      #pragma unroll
      for (int r = 0; r < 4; ++r)
        C[(size_t)(m0 + wm*64 + i*16 + q4 + r)*1024 + n0 + wn*64 + j*16 + l15]
          = acc[i][j][r];
}

// ---------------------------------------------------------------------------
// NN GEMM bf16 with fp32 accumulate-into-C:
// C[M][1024] += A[M][2048] @ B[2048][1024]   (per-batch via blockIdx.z)
// ---------------------------------------------------------------------------
__global__ __launch_bounds__(256) void gemm_nn_add(
    const u16* __restrict__ A0, const u16* __restrict__ B0, float* __restrict__ C0)
{
  const int tid = threadIdx.x;
  const int lane = tid & 63, wave = tid >> 6;
  const int wm = wave >> 1, wn = wave & 1;
  const int l15 = lane & 15, quad = lane >> 4;
  const int m0 = blockIdx.y * 128, n0 = blockIdx.x * 128;
  const u16* A = A0 + (size_t)blockIdx.z * Nx * Nx;
  const u16* B = B0 + (size_t)blockIdx.z * Nx * Dx;
  float*     C = C0 + (size_t)blockIdx.z * Nx * Dx;
  __shared__ u16 As[128*32];
  __shared__ u16 Bs[128*40];
  f32x4 acc[4][4] = {};
  const int srow0 = tid >> 2, scol = tid & 3;
  const int srow1 = (tid + 256) >> 2;
  const int kp  = tid >> 4;
  const int nc8 = (tid & 15) * 8;
  for (int k0 = 0; k0 < Nx; k0 += 32) {
    ushort8 a0 = *(const ushort8*)&A[(size_t)(m0 + srow0)*Nx + k0 + scol*8];
    ushort8 a1 = *(const ushort8*)&A[(size_t)(m0 + srow1)*Nx + k0 + scol*8];
    ushort8 b0 = *(const ushort8*)&B[(size_t)(k0 + 2*kp    )*Dx + n0 + nc8];
    ushort8 b1 = *(const ushort8*)&B[(size_t)(k0 + 2*kp + 1)*Dx + n0 + nc8];
    __syncthreads();
    *(ushort8*)&As[srow0*32 + scol*8] = a0;
    *(ushort8*)&As[srow1*32 + scol*8] = a1;
    #pragma unroll
    for (int j = 0; j < 8; ++j){
      int n = nc8 + j;
      int slot = kp ^ (((n >> 3) & 3) << 2);
      *(u32*)&Bs[n*40 + slot*2] = (u32)(u16)b0[j] | ((u32)(u16)b1[j] << 16);
    }
    __syncthreads();
    short8 af[4], bfr[4];
    #pragma unroll
    for (int i = 0; i < 4; ++i) af[i] = lds8(&As[(wm*64 + i*16 + l15)*32 + quad*8]);
    #pragma unroll
    for (int j = 0; j < 4; ++j){
      int n = wn*64 + j*16 + l15;
      int q2 = quad ^ ((n >> 3) & 3);
      bfr[j] = lds8(&Bs[n*40 + q2*8]);
    }
    #pragma unroll
    for (int i = 0; i < 4; ++i)
      #pragma unroll
      for (int j = 0; j < 4; ++j)
        acc[i][j] = MFMA(af[i], bfr[j], acc[i][j]);
  }
  const int q4 = quad*4;
  #pragma unroll
  for (int i = 0; i < 4; ++i)
    #pragma unroll
    for (int j = 0; j < 4; ++j)
      #pragma unroll
      for (int r = 0; r < 4; ++r){
        size_t idx = (size_t)(m0 + wm*64 + i*16 + q4 + r)*Dx + n0 + wn*64 + j*16 + l15;
        C[idx] += acc[i][j][r];
      }
}

// ---------------------------------------------------------------------------
// diag_k: Dbuf[b][row] = x[b][row] . x[b][row]  (exact fp32)
// ---------------------------------------------------------------------------
__global__ __launch_bounds__(256) void diag_k(const u16* __restrict__ x,
                                              float* __restrict__ Dbuf)
{
  const int b = blockIdx.y;
  const int row = blockIdx.x*64 + (threadIdx.x >> 2);
  const int part = threadIdx.x & 3;
  float s = 0.f;
  #pragma unroll
  for (int i = 0; i < 32; ++i) {
    short8 v = *(const short8*)&x[(size_t)b*Nx*Dx + (size_t)row*Dx + part*256 + i*8];
    #pragma unroll
    for (int k = 0; k < 8; ++k){ float f = bf2f((u16)v[k]); s += f*f; }
  }
  s += __shfl_xor(s, 1); s += __shfl_xor(s, 2);
  if (part == 0) Dbuf[b*2048 + row] = s;
}

// ---------------------------------------------------------------------------
// attnA: no-max flash, split-K x2. grid (32 qt, 32 hb, 2 split) x 256 thr.
// v16 structure (gather loads, barrier-free), unroll 4, prt QUAD-buffer.
// ---------------------------------------------------------------------------
__global__ __launch_bounds__(256, 4) void attnA(
    const u16* __restrict__ Qbuf, const u16* __restrict__ K16,
    const u16* __restrict__ wkwq,
    const u16* __restrict__ Vb0, const u16* __restrict__ Vb1a,
    const u16* __restrict__ Vb1b, const u16* __restrict__ xxt,
    const float* __restrict__ Dbuf,
    u16* __restrict__ O1, u16* __restrict__ O2,
    float* __restrict__ L1, float* __restrict__ L2)
{
  __shared__ __align__(16) u16 prt[4*2560];   // [4 waves][4 bufs][640]
  const int tid = threadIdx.x;
  const int lane = tid & 63, w = tid >> 6;
  const int l15 = lane & 15, quad = lane >> 4, q4 = quad*4;
  const int hb = blockIdx.y;
  const int c = hb & 15, b = hb >> 4;
  const int qt = blockIdx.x;
  const int sp = blockIdx.z;
  const int kt0 = sp * 32;
  const size_t xbase  = (size_t)b * Nx * Dx;
  const size_t xxbase = (size_t)b * Nx * Nx;
  const int row0 = qt*64 + w*16;

  u16* prtw = prt + w*2560;
  u16*  Osp = sp ? O2 : O1;
  float* Lsp = sp ? L2 : L1;
  const int mtd = (row0 >> 5) - kt0;          // only this iter can hit diagonal

  short8 qf[2];
  #pragma unroll
  for (int s = 0; s < 2; ++s)
    qf[s] = *(const short8*)&Qbuf[(size_t)(b*2048 + row0 + l15)*1024 + c*64 + s*32 + quad*8];
  float dv[4];
  #pragma unroll
  for (int r = 0; r < 4; ++r) dv[r] = Dbuf[b*2048 + row0 + q4 + r];
  const float wkh = bf2f(wkwq[c]) * L2E;

  f32x4 O[4] = {};
  float lrun[4] = {0.f, 0.f, 0.f, 0.f};

  const u16* pk  = K16 + xbase + (size_t)(kt0*32 + l15)*Dx + c*64;
  const u16* pxx = xxt + xxbase + (size_t)(row0 + q4)*Nx + kt0*32 + l15;
  const u16* vbp; int dof;
  if (b == 0){ vbp = Vb0; dof = 0; }
  else if (c < 8){ vbp = Vb1a; dof = 0; }
  else { vbp = Vb1b; dof = 512; }
  const u16* pv = vbp + (size_t)(c*64 - dof + l15)*Nx + kt0*32;

  #pragma unroll 4
  for (int mt = 0; mt < 32; ++mt) {
    u16* pw = prtw + (mt & 3)*640;            // quad-buffer: decouple 4 bodies
    float xb[2][4];
    #pragma unroll
    for (int s = 0; s < 2; ++s)
      #pragma unroll
      for (int r = 0; r < 4; ++r)
        xb[s][r] = bf2f(pxx[r*Nx + s*16]);
    short8 kf[2][2];
    #pragma unroll
    for (int s = 0; s < 2; ++s)
      #pragma unroll
      for (int k2 = 0; k2 < 2; ++k2)
        kf[s][k2] = *(const short8*)&pk[s*16*Dx + k2*32 + quad*8];
    short8 vf[4];
    #pragma unroll
    for (int dt = 0; dt < 4; ++dt)
      vf[dt] = *(const short8*)&pv[dt*16*Nx + quad*8];
    f32x4 t2[2];
    #pragma unroll
    for (int s = 0; s < 2; ++s){
      f32x4 t = {};
      t = MFMA(qf[0], kf[s][0], t);
      t = MFMA(qf[1], kf[s][1], t);
      t2[s] = t;
    }
    if (mt == mtd) {                          // wave-uniform branch
      const int kb = (kt0 + mt)*32 + l15;
      #pragma unroll
      for (int s = 0; s < 2; ++s)
        #pragma unroll
        for (int r = 0; r < 4; ++r){
          const int ng = row0 + q4 + r;
          float bias = (kb + s*16 == ng) ? dv[r] : xb[s][r];
          float p = exp2f(t2[s][r] + wkh*bias);
          lrun[r] += p;
          pw[(q4+r)*40 + s*16 + l15] = f2bf(p);
        }
    } else {
      #pragma unroll
      for (int s = 0; s < 2; ++s)
        #pragma unroll
        for (int r = 0; r < 4; ++r){
          float p = exp2f(t2[s][r] + wkh*xb[s][r]);
          lrun[r] += p;
          pw[(q4+r)*40 + s*16 + l15] = f2bf(p);
        }
    }
    short8 pf = lds8(&pw[l15*40 + quad*8]);
    #pragma unroll
    for (int dt = 0; dt < 4; ++dt) O[dt] = MFMA(pf, vf[dt], O[dt]);
    pk += 32*Dx; pxx += 32; pv += 32;
  }

  // cross-lane l sum (within the 16-lane group owning these rows)
  #pragma unroll
  for (int r = 0; r < 4; ++r){
    float l = lrun[r];
    l += __shfl_xor(l, 1); l += __shfl_xor(l, 2);
    l += __shfl_xor(l, 4); l += __shfl_xor(l, 8);
    lrun[r] = l;
  }
  #pragma unroll
  for (int dt = 0; dt < 4; ++dt)
    #pragma unroll
    for (int r = 0; r < 4; ++r)
      Osp[(size_t)(b*2048 + row0 + q4 + r)*1024 + c*64 + dt*16 + l15]
        = f2bf(O[dt][r]);
  if (l15 == 0){
    #pragma unroll
    for (int r = 0; r < 4; ++r)
      Lsp[(size_t)(b*2048 + row0 + q4 + r)*16 + c] = lrun[r];
  }
}

// ---------------------------------------------------------------------------
// attnM: merge splits. Obuf = (O1+O2) * il,  il = 1/(l1+l2); emit Sil.
// ---------------------------------------------------------------------------
__global__ __launch_bounds__(128) void attnM(
    const u16* __restrict__ O1, const u16* __restrict__ O2,
    const float* __restrict__ L1, const float* __restrict__ L2,
    u16* __restrict__ Obuf, float* __restrict__ Sil)
{
  const int row = blockIdx.x;
  const int t = threadIdx.x;
  const int h = t >> 3;
  const float il = 1.0f / fmaxf(L1[(size_t)row*16 + h] + L2[(size_t)row*16 + h], 1e-30f);
  short8 a = *(const short8*)&O1[(size_t)row*1024 + t*8];
  short8 b = *(const short8*)&O2[(size_t)row*1024 + t*8];
  ushort8 o;
  #pragma unroll
  for (int j = 0; j < 8; ++j)
    o[j] = f2bf((bf2f((u16)a[j]) + bf2f((u16)b[j])) * il);
  *(ushort8*)&Obuf[(size_t)row*1024 + t*8] = o;
  if ((t & 7) == 0) Sil[(size_t)row*16 + h] = il;
}

// ---------------------------------------------------------------------------
// attnB: PSA half = sum over 8 heads of wvh*il_h*exp2(sv_h), 64x64 tiles.
// grid (32 kt, 32 qt, 4 = b*? ) : b = z&1, hs = z>>1 (heads hs*8..hs*8+7).
// Writes PSH[hs][b][q][k].
// ---------------------------------------------------------------------------
__global__ __launch_bounds__(256, 4) void attnB(
    const u16* __restrict__ Qbuf, const u16* __restrict__ K16,
    const u16* __restrict__ wkwq, const u16* __restrict__ wvwo,
    const u16* __restrict__ xxt, const float* __restrict__ Sil,
    const float* __restrict__ Dbuf, u16* __restrict__ PSH)
{
  __shared__ float sst[1024];                // [64 rows][16 h] il
  const int tid = threadIdx.x;
  const int lane = tid & 63, w = tid >> 6;
  const int l15 = lane & 15, quad = lane >> 4, q4 = quad*4;
  const int kt = blockIdx.x, qt = blockIdx.y;
  const int b = blockIdx.z & 1, hs = blockIdx.z >> 1;
  const int h0 = hs*8;
  const size_t xbase  = (size_t)b * Nx * Dx;
  const size_t xxbase = (size_t)b * Nx * Nx;
  u16* dst = PSH + ((size_t)(hs*2 + b)) * Nx * Nx;

  {
    const float* src = Sil + ((size_t)b*2048 + qt*64)*16;
    for (int i = tid; i < 1024; i += 256) sst[i] = src[i];
  }
  __syncthreads();

  const int rloc = w*16 + q4;
  float xbv[4][4];
  #pragma unroll
  for (int ks = 0; ks < 4; ++ks)
    #pragma unroll
    for (int r = 0; r < 4; ++r){
      int gr = qt*64 + rloc + r;
      int gc = kt*64 + ks*16 + l15;
      float v = bf2f(xxt[xxbase + (size_t)gr*Nx + gc]);
      if (gr == gc) v = Dbuf[b*2048 + gr];
      xbv[ks][r] = v;
    }

  f32x4 psa_[4] = {};
  #pragma unroll 2
  for (int hh = 0; hh < 8; ++hh){
    const int h = h0 + hh;
    const float wkh = bf2f(wkwq[h]) * L2E;
    const float wvh = bf2f(wvwo[h]);
    short8 qf[2];
    #pragma unroll
    for (int s = 0; s < 2; ++s)
      qf[s] = *(const short8*)&Qbuf[(size_t)(b*2048 + qt*64 + w*16 + l15)*1024 + h*64 + s*32 + quad*8];
    short8 kf[4][2];
    #pragma unroll
    for (int ks = 0; ks < 4; ++ks)
      #pragma unroll
      for (int k2 = 0; k2 < 2; ++k2)
        kf[ks][k2] = *(const short8*)&K16[xbase + (size_t)(kt*64 + ks*16 + l15)*Dx + h*64 + k2*32 + quad*8];
    #pragma unroll
    for (int ks = 0; ks < 4; ++ks){
      f32x4 t = {};
      t = MFMA(qf[0], kf[ks][0], t);
      t = MFMA(qf[1], kf[ks][1], t);
      #pragma unroll
      for (int r = 0; r < 4; ++r){
        float ilw = sst[(rloc + r)*16 + h] * wvh;
        psa_[ks][r] += exp2f(t[r] + wkh*xbv[ks][r]) * ilw;
      }
    }
  }
  #pragma unroll
  for (int ks = 0; ks < 4; ++ks)
    #pragma unroll
    for (int r = 0; r < 4; ++r)
      dst[(size_t)(qt*64 + rloc + r)*Nx + kt*64 + ks*16 + l15]
        = f2bf(psa_[ks][r]);
}

// ---------------------------------------------------------------------------
// addp: PSA[b] = PSH[0][b] + PSH[1][b]  (bf16, vectorized grid-stride)
// n in short8 units over the full 2-batch PSA (2*Nx*Nx elements).
// ---------------------------------------------------------------------------
__global__ __launch_bounds__(256) void addp(const u16* __restrict__ PSH,
                                            u16* __restrict__ PSA)
{
  const size_t half = (size_t)2 * Nx * Nx;          // elements in one hs-plane
  size_t i = ((size_t)blockIdx.x*256 + threadIdx.x) * 8;
  const size_t stride = (size_t)gridDim.x * 256 * 8;
  for (; i < half; i += stride){
    short8 a = *(const short8*)&PSH[i];
    short8 b = *(const short8*)&PSH[half + i];
    ushort8 o;
    #pragma unroll
    for (int j = 0; j < 8; ++j)
      o[j] = f2bf(bf2f((u16)a[j]) + bf2f((u16)b[j]));
    *(ushort8*)&PSA[i] = o;
  }
}

// ---------------------------------------------------------------------------
// attn2 (v13 path, verified) — fallback if ws in [16MB, NEED)
// ---------------------------------------------------------------------------
#define B_PRT 0
#define B_PSP 20480
#define B_DG  61440
#define B_SZ  86016

__global__ __launch_bounds__(1024)
__attribute__((amdgpu_waves_per_eu(4, 4)))
void attn2(
    const u16* __restrict__ x, const u16* __restrict__ wq,
    const u16* __restrict__ wo, const u16* __restrict__ wkwq,
    const u16* __restrict__ wvwo, const u16* __restrict__ K16,
    const u16* __restrict__ Vb0, const u16* __restrict__ Vb1a,
    const u16* __restrict__ Vb1b, u16* __restrict__ PSA,
    float* out)
{
  __shared__ __align__(16) u8 AR[B_SZ];
  const int tid = threadIdx.x;
  const int lane = tid & 63, c = tid >> 6;
  const int l15 = lane & 15, quad = lane >> 4, q4 = quad*4;
  int bb = blockIdx.x; bb = (bb & 7)*32 + (bb >> 3);
  const int b = bb >> 7, n0 = (bb & 127) * 16;
  const size_t xbase = (size_t)b * Nx * Dx;
  const u16* xxt = (const u16*)out;
  const size_t xxbase = (size_t)b * Nx * Nx;
  u16* psag = PSA + (size_t)b * Nx * Nx;

  u16*   prt = (u16*)(AR + B_PRT);
  u16*   psp = (u16*)(AR + B_PSP);
  float* dgv = (float*)(AR + B_DG);
  u16*   qrt = (u16*)(AR + 0) + c*(16*72);

  {
    f32x4 qacc[4] = {};
    #pragma unroll 1
    for (int kc = 0; kc < 32; ++kc) {
      short8 af = *(const short8*)&x[xbase + (size_t)(n0 + l15)*Dx + kc*32 + quad*8];
      #pragma unroll
      for (int j = 0; j < 4; ++j) {
        short8 bf = *(const short8*)&wq[(size_t)(c*64 + j*16 + l15)*Dx + kc*32 + quad*8];
        qacc[j] = MFMA(af, bf, qacc[j]);
      }
    }
    const float qs = SCALEx * L2E;
    #pragma unroll
    for (int j = 0; j < 4; ++j)
      #pragma unroll
      for (int r = 0; r < 4; ++r)
        qrt[(q4+r)*72 + j*16 + l15] = f2bf(qacc[j][r] * qs);
  }
  {
    float s = 0.f;
    #pragma unroll
    for (int p = 0; p < 2; ++p) {
      short8 v = *(const short8*)&x[xbase + (size_t)(n0+c)*Dx + p*512 + lane*8];
      #pragma unroll
      for (int i = 0; i < 8; ++i){ float f = bf2f((u16)v[i]); s += f*f; }
    }
    #pragma unroll
    for (int o = 1; o < 64; o <<= 1) s += __shfl_xor(s, o);
    if (lane == 0) dgv[c] = s;
  }
  short8 qf[2];
  #pragma unroll
  for (int s = 0; s < 2; ++s) qf[s] = lds8(&qrt[l15*72 + s*32 + quad*8]);
  __syncthreads();
  float dv[4];
  #pragma unroll
  for (int r = 0; r < 4; ++r) dv[r] = dgv[q4+r];
  __syncthreads();

  const float wkh = bf2f(wkwq[c]) * L2E;
  const float wvh = bf2f(wvwo[c]);

  float mrun[4], lrun[4];
  #pragma unroll
  for (int r = 0; r < 4; ++r){ mrun[r] = -1e30f; lrun[r] = 0.f; }

  const u16* pk  = K16 + xbase + (size_t)l15*Dx + c*64;
  const u16* pxx = xxt + xxbase + (size_t)(n0+q4)*Nx + l15;

  #pragma unroll 2
  for (int mt = 0; mt < 64; ++mt) {
    float xb[2][4];
    #pragma unroll
    for (int s = 0; s < 2; ++s)
      #pragma unroll
      for (int r = 0; r < 4; ++r)
        xb[s][r] = bf2f(pxx[r*Nx + s*16]);
    short8 kf[2][2];
    #pragma unroll
    for (int s = 0; s < 2; ++s)
      #pragma unroll
      for (int k2 = 0; k2 < 2; ++k2)
        kf[s][k2] = *(const short8*)&pk[s*16*Dx + k2*32 + quad*8];
    f32x4 t2[2];
    #pragma unroll
    for (int s = 0; s < 2; ++s){
      f32x4 t = {};
      t = MFMA(qf[0], kf[s][0], t);
      t = MFMA(qf[1], kf[s][1], t);
      t2[s] = t;
    }
    const int kb = mt*32 + l15;
    #pragma unroll
    for (int r = 0; r < 4; ++r){
      const int ng = n0 + q4 + r;
      float b0 = (kb      == ng) ? dv[r] : xb[0][r];
      float b1 = (kb + 16 == ng) ? dv[r] : xb[1][r];
      float sv0 = t2[0][r] + wkh*b0;
      float sv1 = t2[1][r] + wkh*b1;
      float m2 = fmaxf(sv0, sv1);
      float mn = fmaxf(mrun[r], m2);
      lrun[r] = lrun[r]*exp2f(mrun[r]-mn) + exp2f(sv0-mn) + exp2f(sv1-mn);
      mrun[r] = mn;
    }
    pk += 32*Dx; pxx += 32;
  }
  float ms[4], il[4];
  #pragma unroll
  for (int r = 0; r < 4; ++r){
    float mr = mrun[r];
    #pragma unroll
    for (int o = 1; o < 16; o <<= 1) mr = fmaxf(mr, __shfl_xor(mr, o));
    float ls = lrun[r]*exp2f(mrun[r]-mr);
    #pragma unroll
    for (int o = 1; o < 16; o <<= 1) ls += __shfl_xor(ls, o);
    ms[r] = mr; il[r] = 1.0f/fmaxf(ls, 1e-30f);
  }

  f32x4 O[4] = {};
  const u16* vbp; int voff;
  if (b == 0){ vbp = Vb0; voff = 0; }
  else if (c < 8){ vbp = Vb1a; voff = 0; }
  else { vbp = Vb1b; voff = 512; }
  const u16* pv = vbp + (size_t)(c*64 - voff + l15)*Nx;
  pk  = K16 + xbase + (size_t)l15*Dx + c*64;
  pxx = xxt + xxbase + (size_t)(n0+q4)*Nx + l15;

  #pragma unroll 1
  for (int mt = 0; mt < 64; ++mt) {
    float xb[2][4];
    #pragma unroll
    for (int s = 0; s < 2; ++s)
      #pragma unroll
      for (int r = 0; r < 4; ++r)
        xb[s][r] = bf2f(pxx[r*Nx + s*16]);
    short8 kf[2][2];
    #pragma unroll
    for (int s = 0; s < 2; ++s)
      #pragma unroll
      for (int k2 = 0; k2 < 2; ++k2)
        kf[s][k2] = *(const short8*)&pk[s*16*Dx + k2*32 + quad*8];
    short8 vf[4];
    #pragma unroll
    for (int dt = 0; dt < 4; ++dt)
      vf[dt] = *(const short8*)&pv[dt*16*Nx + quad*8];
    f32x4 t2[2];
    #pragma unroll
    for (int s = 0; s < 2; ++s){
      f32x4 t = {};
      t = MFMA(qf[0], kf[s][0], t);
      t = MFMA(qf[1], kf[s][1], t);
      t2[s] = t;
    }
    const int kb = mt*32 + l15;
    u16* pspw = psp + (mt & 1)*10240;
    #pragma unroll
    for (int s = 0; s < 2; ++s)
      #pragma unroll
      for (int r = 0; r < 4; ++r){
        const int ng = n0 + q4 + r;
        float bias = (kb + s*16 == ng) ? dv[r] : xb[s][r];
        float sv = t2[s][r] + wkh*bias;
        float p = exp2f(fminf(sv - ms[r], 0.f)) * il[r];
        prt[c*640 + (q4+r)*40 + s*16 + l15] = f2bf(p);
        pspw[c*640 + (q4+r)*40 + s*16 + l15] = f2bf(wvh * p);
      }
    short8 pf = lds8(&prt[c*640 + l15*40 + quad*8]);
    #pragma unroll
    for (int dt = 0; dt < 4; ++dt) O[dt] = MFMA(pf, vf[dt], O[dt]);
    __syncthreads();
    if (tid < 512){
      const int qq = tid >> 5, mm = tid & 31;
      float v = 0.f;
      #pragma unroll
      for (int w = 0; w < 16; ++w) v += bf2f(pspw[w*640 + qq*40 + mm]);
      psag[(size_t)(n0 + qq)*Nx + mt*32 + mm] = f2bf(v);
    }
    pk += 32*Dx; pxx += 32; pv += 32;
  }

  __syncthreads();
  u16* ol = (u16*)(AR + 0);
  #pragma unroll
  for (int dt = 0; dt < 4; ++dt)
    #pragma unroll
    for (int r = 0; r < 4; ++r)
      ol[(q4+r)*1040 + c*64 + dt*16 + l15] = f2bf(O[dt][r]);
  __syncthreads();
  f32x4 Uo[4] = {};
  #pragma unroll 1
  for (int kc = 0; kc < 32; ++kc){
    short8 af = lds8(&ol[l15*1040 + kc*32 + quad*8]);
    #pragma unroll
    for (int ct = 0; ct < 4; ++ct){
      short8 bw = *(const short8*)&wo[(size_t)(c*64 + ct*16 + l15)*Dx + kc*32 + quad*8];
      Uo[ct] = MFMA(af, bw, Uo[ct]);
    }
  }
  #pragma unroll
  for (int ct = 0; ct < 4; ++ct)
    #pragma unroll
    for (int r = 0; r < 4; ++r)
      out[xbase + (size_t)(n0+q4+r)*Dx + c*64 + ct*16 + l15] = Uo[ct][r];
}

// ---------------------------------------------------------------------------
extern "C" void kernel_launch(void* const* d_in, const int* in_sizes, int n_in,
                              void* d_out, int out_size, void* d_ws, size_t ws_size,
                              hipStream_t stream) {
  u16* x16   = (u16*)d_in[0];
  u16* K16   = x16 + 4u*1024u*1024u;
  u16* wqk16 = (u16*)d_in[1];
  u16* Vb0   = wqk16 + 2u*1024u*1024u;
  u16* wv16  = (u16*)d_in[2];
  u16* Vb1a  = wv16 + 1024u*1024u;
  u16* wo16  = (u16*)d_in[3];
  u16* Vb1b  = wo16 + 1024u*1024u;
  float* outF = (float*)d_out;
  u16* S = (u16*)d_out;

  const float loW = 0.000244140625f, hiW = 0.25f;
  conv_w<<<dim3(512), 256, 0, stream>>>(d_in[0], S, 4*1024*1024, 512, 0.00390625f, 16.0f);
  copyb <<<dim3(512), 256, 0, stream>>>(S, x16, 4*1024*1024);
  conv_w<<<dim3(256), 256, 0, stream>>>(d_in[1], S, 2*1024*1024, 512, loW, hiW);
  copyb <<<dim3(256), 256, 0, stream>>>(S, wqk16, 2*1024*1024);
  conv_w<<<dim3(128), 256, 0, stream>>>(d_in[2], S, 1024*1024, 512, loW, hiW);
  copyb <<<dim3(128), 256, 0, stream>>>(S, wv16, 1024*1024);
  conv_w<<<dim3(128), 256, 0, stream>>>(d_in[3], S, 1024*1024, 512, loW, hiW);
  copyb <<<dim3(128), 256, 0, stream>>>(S, wo16, 1024*1024);
  conv_small<<<dim3(1), 64, 0, stream>>>((void*)d_in[4], 16, loW, hiW);
  conv_small<<<dim3(1), 64, 0, stream>>>((void*)d_in[5], 16, loW, hiW);

  // ws layout (bytes)
  const size_t OFF_PSA = 0;              // 16 MB (merged PSA)
  const size_t OFF_Q   = 16777216;       //  8 MB
  const size_t OFF_OB  = 25165824;       //  8 MB (normalized O)
  const size_t OFF_O1  = 33554432;       //  8 MB
  const size_t OFF_O2  = 41943040;       //  8 MB
  const size_t OFF_L1  = 50331648;       // 256 KB
  const size_t OFF_L2  = 50593792;       // 256 KB
  const size_t OFF_SI  = 50855936;       // 256 KB
  const size_t OFF_D   = 51118080;       //  16 KB
  const size_t OFF_PSH = 52428800;       // 32 MB (PSA halves [hs][b])
  const size_t NEED    = 52428800 + 33554432;

  // K = x @ wk^T (both batches)
  gemm_bf16<<<dim3(8, 32), 256, 0, stream>>>(x16, wqk16 + 1024u*1024u, K16, 1024, 1.0f);
  // V^T = wv @ x^T
  gemm_bf16<<<dim3(16, 8), 256, 0, stream>>>(wv16, x16, Vb0, 2048, 1.0f);
  gemm_bf16<<<dim3(16, 4), 256, 0, stream>>>(wv16,              x16 + 2048u*1024u, Vb1a, 2048, 1.0f);
  gemm_bf16<<<dim3(16, 4), 256, 0, stream>>>(wv16 + 512u*1024u, x16 + 2048u*1024u, Vb1b, 2048, 1.0f);
  // XXT = x @ x^T (bf16) into d_out
  gemm_bf16<<<dim3(16, 16), 256, 0, stream>>>(x16,               x16,               (u16*)d_out,                  2048, 1.0f);
  gemm_bf16<<<dim3(16, 16), 256, 0, stream>>>(x16 + 2048u*1024u, x16 + 2048u*1024u, (u16*)d_out + 4u*1024u*1024u, 2048, 1.0f);

  if (d_ws != nullptr && ws_size >= NEED) {
    u8* ws = (u8*)d_ws;
    // Q = (x @ wq^T) * SCALE*log2e
    gemm_bf16<<<dim3(8, 32), 256, 0, stream>>>(x16, wqk16, (u16*)(ws + OFF_Q), 1024, SCALEx * L2E);
    diag_k<<<dim3(32, 2), 256, 0, stream>>>(x16, (float*)(ws + OFF_D));
    attnA<<<dim3(32, 32, 2), 256, 0, stream>>>(
        (const u16*)(ws + OFF_Q), K16, (const u16*)d_in[4],
        Vb0, Vb1a, Vb1b, (const u16*)d_out, (const float*)(ws + OFF_D),
        (u16*)(ws + OFF_O1), (u16*)(ws + OFF_O2),
        (float*)(ws + OFF_L1), (float*)(ws + OFF_L2));
    attnM<<<dim3(4096), 128, 0, stream>>>(
        (const u16*)(ws + OFF_O1), (const u16*)(ws + OFF_O2),
        (const float*)(ws + OFF_L1), (const float*)(ws + OFF_L2),
        (u16*)(ws + OFF_OB), (float*)(ws + OFF_SI));
    attnB<<<dim3(32, 32, 4), 256, 0, stream>>>(
        (const u16*)(ws + OFF_Q), K16, (const u16*)d_in[4], (const u16*)d_in[5],
        (const u16*)d_out, (const float*)(ws + OFF_SI), (const float*)(ws + OFF_D),
        (u16*)(ws + OFF_PSH));
    addp<<<dim3(2048), 256, 0, stream>>>((const u16*)(ws + OFF_PSH), (u16*)(ws + OFF_PSA));
    gemm_nt_f32<<<dim3(8, 32), 256, 0, stream>>>((const u16*)(ws + OFF_OB), wo16, outF);
    gemm_nn_add<<<dim3(8, 16, 2), 256, 0, stream>>>((const u16*)(ws + OFF_PSA), x16, outF);
  } else if (d_ws != nullptr && ws_size >= (size_t)2*2048*2048*2) {
    attn2<<<dim3(256), 1024, 0, stream>>>(x16, wqk16, wo16,
        (const u16*)d_in[4], (const u16*)d_in[5], K16, Vb0, Vb1a, Vb1b,
        (u16*)d_ws, outF);
    gemm_nn_add<<<dim3(8, 16, 2), 256, 0, stream>>>((const u16*)d_ws, x16, outF);
  }
}

// Round 12
// 630.668 us; speedup vs baseline: 1.4830x; 1.4536x over previous
//
// v19: fragment-PACKED K/V/Q layouts. All kf/vf/qf loads in attnA/attnB were
// 16-row gathers (16 scattered cache lines per instr; ~34M scattered L2
// transactions in attnA alone). K/V/Q are produced by our own GEMMs -> write
// them in MFMA-fragment order (1KB lane-linear units) via modified epilogues
// (same scattered-scalar store count = zero extra cost). Every fragment load
// becomes ONE coalesced 1KB wave read. attnB reverted to verified v16 form
// (single pass, PSA direct; addp/PSH dropped - v18 regression). attnA keeps
// v18 loop (unroll4, quad prt). Fallback (ws small): old linear gemms + attn2.
#include <hip/hip_runtime.h>

typedef unsigned short u16;
typedef unsigned int   u32;
typedef unsigned char  u8;
typedef __attribute__((ext_vector_type(8))) short          short8;
typedef __attribute__((ext_vector_type(8))) unsigned short ushort8;
typedef __attribute__((ext_vector_type(4))) float          f32x4;

#define MFMA(a,b,c) __builtin_amdgcn_mfma_f32_16x16x32_bf16((a),(b),(c),0,0,0)
#define Nx 2048
#define Dx 1024
#define SCALEx 0.125f
#define L2E 1.4426950408889634f

__device__ __forceinline__ float bf2f(u16 u){ u32 x=((u32)u)<<16; return __builtin_bit_cast(float,x); }
__device__ __forceinline__ u16 f2bf(float f){ u32 u=__builtin_bit_cast(u32,f); u32 r=(u+0x7FFFu+((u>>16)&1u))>>16; return (u16)r; }
__device__ __forceinline__ short8 lds8(const u16* p){ return *(const short8*)p; }

// ---- dtype normalization (identity if already bf16) ----
__device__ int looks_bf16_dev(const u16* p, int nsamp, float lo, float hi){
  int cnt = 0;
  for (int i = 0; i < nsamp; ++i){
    float a = fabsf(bf2f(p[2*i]));
    if (a >= lo && a <= hi) cnt++;
  }
  return (2*cnt > nsamp) ? 1 : 0;
}

__global__ __launch_bounds__(256) void conv_w(const void* __restrict__ in, u16* __restrict__ S,
                                              int n, int nsamp, float lo, float hi){
  __shared__ int flag;
  if (threadIdx.x == 0) flag = looks_bf16_dev((const u16*)in, nsamp, lo, hi);
  __syncthreads();
  const int isbf = flag;
  int i = blockIdx.x*256 + threadIdx.x;
  int stride = gridDim.x*256;
  if (isbf){
    const u16* pu = (const u16*)in;
    for (; i < n; i += stride) S[i] = pu[i];
  } else {
    const float* pf = (const float*)in;
    for (; i < n; i += stride) S[i] = f2bf(pf[i]);
  }
}

__global__ __launch_bounds__(256) void copyb(const u16* __restrict__ S, u16* __restrict__ dst, int n){
  int i = blockIdx.x*256 + threadIdx.x;
  int stride = gridDim.x*256;
  for (; i < n; i += stride) dst[i] = S[i];
}

__global__ void conv_small(void* buf, int n, float lo, float hi){
  __shared__ float tmp[64];
  __shared__ int flag;
  int t = threadIdx.x;
  if (t == 0) flag = looks_bf16_dev((const u16*)buf, n/2, lo, hi);
  __syncthreads();
  if (t < n) tmp[t] = flag ? bf2f(((const u16*)buf)[t]) : ((const float*)buf)[t];
  __syncthreads();
  if (t < n) ((u16*)buf)[t] = f2bf(tmp[t]);
}

// ---------------------------------------------------------------------------
// Shared GEMM main-loop macro body (A[M][1024] @ Bt[N][1024]^T, K=1024).
// Each variant differs only in the epilogue.
// ---------------------------------------------------------------------------
#define GEMM_BODY \
  const int tid = threadIdx.x; \
  const int lane = tid & 63, wave = tid >> 6; \
  const int wm = wave >> 1, wn = wave & 1; \
  const int l15 = lane & 15, quad = lane >> 4; \
  const int m0 = blockIdx.y * 128, n0 = blockIdx.x * 128; \
  __shared__ u16 As[128*32], Bs[128*32]; \
  f32x4 acc[4][4] = {}; \
  const int srow0 = tid >> 2, scol = tid & 3; \
  const int srow1 = (tid + 256) >> 2; \
  for (int k0 = 0; k0 < 1024; k0 += 32) { \
    ushort8 a0 = *(const ushort8*)&A [(size_t)(m0 + srow0)*1024 + k0 + scol*8]; \
    ushort8 b0 = *(const ushort8*)&Bt[(size_t)(n0 + srow0)*1024 + k0 + scol*8]; \
    ushort8 a1 = *(const ushort8*)&A [(size_t)(m0 + srow1)*1024 + k0 + scol*8]; \
    ushort8 b1 = *(const ushort8*)&Bt[(size_t)(n0 + srow1)*1024 + k0 + scol*8]; \
    __syncthreads(); \
    *(ushort8*)&As[srow0*32 + scol*8] = a0; \
    *(ushort8*)&Bs[srow0*32 + scol*8] = b0; \
    *(ushort8*)&As[srow1*32 + scol*8] = a1; \
    *(ushort8*)&Bs[srow1*32 + scol*8] = b1; \
    __syncthreads(); \
    short8 af[4], bfr[4]; \
    _Pragma("unroll") \
    for (int i = 0; i < 4; ++i) af[i]  = lds8(&As[(wm*64 + i*16 + l15)*32 + quad*8]); \
    _Pragma("unroll") \
    for (int j = 0; j < 4; ++j) bfr[j] = lds8(&Bs[(wn*64 + j*16 + l15)*32 + quad*8]); \
    _Pragma("unroll") \
    for (int i = 0; i < 4; ++i) \
      _Pragma("unroll") \
      for (int j = 0; j < 4; ++j) \
        acc[i][j] = MFMA(af[i], bfr[j], acc[i][j]); \
  } \
  const int q4 = quad*4;

// ---------------------------------------------------------------------------
// NT GEMM bf16: C[M][ldc] = ascale * (A @ Bt^T)   (linear output; fallback/XXT)
// ---------------------------------------------------------------------------
__global__ __launch_bounds__(256) void gemm_bf16(
    const u16* __restrict__ A, const u16* __restrict__ Bt, u16* __restrict__ C,
    int ldc, float ascale)
{
  GEMM_BODY
  #pragma unroll
  for (int i = 0; i < 4; ++i)
    #pragma unroll
    for (int j = 0; j < 4; ++j)
      #pragma unroll
      for (int r = 0; r < 4; ++r)
        C[(size_t)(m0 + wm*64 + i*16 + q4 + r)*ldc + n0 + wn*64 + j*16 + l15]
          = f2bf(acc[i][j][r] * ascale);
}

// ---------------------------------------------------------------------------
// K-packed GEMM: rows = tokens (4096 global), cols = d (1024).
// Kp unit (head, g32=token>>5, s=(token>>4)&1, k2) -> [lane=quad*16+l15][8].
// ---------------------------------------------------------------------------
__global__ __launch_bounds__(256) void gemm_kpack(
    const u16* __restrict__ A, const u16* __restrict__ Bt, u16* __restrict__ Kp)
{
  GEMM_BODY
  #pragma unroll
  for (int i = 0; i < 4; ++i)
    #pragma unroll
    for (int j = 0; j < 4; ++j)
      #pragma unroll
      for (int r = 0; r < 4; ++r){
        int token = m0 + wm*64 + i*16 + q4 + r;
        int dcol  = n0 + wn*64 + j*16 + l15;
        int head = dcol>>6, k2 = (dcol>>5)&1, qd = (dcol>>3)&3, el = dcol&7;
        int g32 = token>>5, s = (token>>4)&1, lp = token&15;
        size_t dst = ((size_t)((head*128 + g32)*4 + s*2 + k2)*64 + qd*16 + lp)*8 + el;
        Kp[dst] = f2bf(acc[i][j][r]);
      }
}

// ---------------------------------------------------------------------------
// Q-packed GEMM (scaled): rows = tokens (4096 global), cols = d (1024).
// Qp unit (r16=row>>4, h, s) -> [lane][8].
// ---------------------------------------------------------------------------
__global__ __launch_bounds__(256) void gemm_qpack(
    const u16* __restrict__ A, const u16* __restrict__ Bt, u16* __restrict__ Qp,
    float ascale)
{
  GEMM_BODY
  #pragma unroll
  for (int i = 0; i < 4; ++i)
    #pragma unroll
    for (int j = 0; j < 4; ++j)
      #pragma unroll
      for (int r = 0; r < 4; ++r){
        int row = m0 + wm*64 + i*16 + q4 + r;
        int col = n0 + wn*64 + j*16 + l15;
        int h = col>>6, s = (col>>5)&1, qd = (col>>3)&3, el = col&7;
        int r16 = row>>4, lp = row&15;
        size_t dst = ((size_t)((r16*16 + h)*2 + s)*64 + qd*16 + lp)*8 + el;
        Qp[dst] = f2bf(acc[i][j][r] * ascale);
      }
}

// ---------------------------------------------------------------------------
// V-packed GEMM: A = wv (rows = d 0..1023), Bt = x[batch] (rows = tokens).
// Vp unit (batch, head, mtb=tok>>5, dt) -> [lane][8].
// ---------------------------------------------------------------------------
__global__ __launch_bounds__(256) void gemm_vpack(
    const u16* __restrict__ A, const u16* __restrict__ Bt, u16* __restrict__ Vp,
    int batch)
{
  GEMM_BODY
  #pragma unroll
  for (int i = 0; i < 4; ++i)
    #pragma unroll
    for (int j = 0; j < 4; ++j)
      #pragma unroll
      for (int r = 0; r < 4; ++r){
        int d_abs = m0 + wm*64 + i*16 + q4 + r;
        int tok   = n0 + wn*64 + j*16 + l15;
        int head = d_abs>>6, dt = (d_abs>>4)&3, lp = d_abs&15;
        int mtb = tok>>5, qd = (tok>>3)&3, el = tok&7;
        size_t dst = ((size_t)(((batch*16 + head)*64 + mtb)*4 + dt)*64 + qd*16 + lp)*8 + el;
        Vp[dst] = f2bf(acc[i][j][r]);
      }
}

// ---------------------------------------------------------------------------
// NT GEMM bf16 -> f32 C: C[M][1024] = A[M][1024] @ Bt[1024][1024]^T
// ---------------------------------------------------------------------------
__global__ __launch_bounds__(256) void gemm_nt_f32(
    const u16* __restrict__ A, const u16* __restrict__ Bt, float* __restrict__ C)
{
  GEMM_BODY
  #pragma unroll
  for (int i = 0; i < 4; ++i)
    #pragma unroll
    for (int j = 0; j < 4; ++j)
      #pragma unroll
      for (int r = 0; r < 4; ++r)
        C[(size_t)(m0 + wm*64 + i*16 + q4 + r)*1024 + n0 + wn*64 + j*16 + l15]
          = acc[i][j][r];
}

// ---------------------------------------------------------------------------
// NN GEMM bf16 with fp32 accumulate-into-C:
// C[M][1024] += A[M][2048] @ B[2048][1024]   (per-batch via blockIdx.z)
// ---------------------------------------------------------------------------
__global__ __launch_bounds__(256) void gemm_nn_add(
    const u16* __restrict__ A0, const u16* __restrict__ B0, float* __restrict__ C0)
{
  const int tid = threadIdx.x;
  const int lane = tid & 63, wave = tid >> 6;
  const int wm = wave >> 1, wn = wave & 1;
  const int l15 = lane & 15, quad = lane >> 4;
  const int m0 = blockIdx.y * 128, n0 = blockIdx.x * 128;
  const u16* A = A0 + (size_t)blockIdx.z * Nx * Nx;
  const u16* B = B0 + (size_t)blockIdx.z * Nx * Dx;
  float*     C = C0 + (size_t)blockIdx.z * Nx * Dx;
  __shared__ u16 As[128*32];
  __shared__ u16 Bs[128*40];
  f32x4 acc[4][4] = {};
  const int srow0 = tid >> 2, scol = tid & 3;
  const int srow1 = (tid + 256) >> 2;
  const int kp  = tid >> 4;
  const int nc8 = (tid & 15) * 8;
  for (int k0 = 0; k0 < Nx; k0 += 32) {
    ushort8 a0 = *(const ushort8*)&A[(size_t)(m0 + srow0)*Nx + k0 + scol*8];
    ushort8 a1 = *(const ushort8*)&A[(size_t)(m0 + srow1)*Nx + k0 + scol*8];
    ushort8 b0 = *(const ushort8*)&B[(size_t)(k0 + 2*kp    )*Dx + n0 + nc8];
    ushort8 b1 = *(const ushort8*)&B[(size_t)(k0 + 2*kp + 1)*Dx + n0 + nc8];
    __syncthreads();
    *(ushort8*)&As[srow0*32 + scol*8] = a0;
    *(ushort8*)&As[srow1*32 + scol*8] = a1;
    #pragma unroll
    for (int j = 0; j < 8; ++j){
      int n = nc8 + j;
      int slot = kp ^ (((n >> 3) & 3) << 2);
      *(u32*)&Bs[n*40 + slot*2] = (u32)(u16)b0[j] | ((u32)(u16)b1[j] << 16);
    }
    __syncthreads();
    short8 af[4], bfr[4];
    #pragma unroll
    for (int i = 0; i < 4; ++i) af[i] = lds8(&As[(wm*64 + i*16 + l15)*32 + quad*8]);
    #pragma unroll
    for (int j = 0; j < 4; ++j){
      int n = wn*64 + j*16 + l15;
      int q2 = quad ^ ((n >> 3) & 3);
      bfr[j] = lds8(&Bs[n*40 + q2*8]);
    }
    #pragma unroll
    for (int i = 0; i < 4; ++i)
      #pragma unroll
      for (int j = 0; j < 4; ++j)
        acc[i][j] = MFMA(af[i], bfr[j], acc[i][j]);
  }
  const int q4 = quad*4;
  #pragma unroll
  for (int i = 0; i < 4; ++i)
    #pragma unroll
    for (int j = 0; j < 4; ++j)
      #pragma unroll
      for (int r = 0; r < 4; ++r){
        size_t idx = (size_t)(m0 + wm*64 + i*16 + q4 + r)*Dx + n0 + wn*64 + j*16 + l15;
        C[idx] += acc[i][j][r];
      }
}

// ---------------------------------------------------------------------------
// diag_k: Dbuf[b][row] = x[b][row] . x[b][row]  (exact fp32)
// ---------------------------------------------------------------------------
__global__ __launch_bounds__(256) void diag_k(const u16* __restrict__ x,
                                              float* __restrict__ Dbuf)
{
  const int b = blockIdx.y;
  const int row = blockIdx.x*64 + (threadIdx.x >> 2);
  const int part = threadIdx.x & 3;
  float s = 0.f;
  #pragma unroll
  for (int i = 0; i < 32; ++i) {
    short8 v = *(const short8*)&x[(size_t)b*Nx*Dx + (size_t)row*Dx + part*256 + i*8];
    #pragma unroll
    for (int k = 0; k < 8; ++k){ float f = bf2f((u16)v[k]); s += f*f; }
  }
  s += __shfl_xor(s, 1); s += __shfl_xor(s, 2);
  if (part == 0) Dbuf[b*2048 + row] = s;
}

// ---------------------------------------------------------------------------
// attnA: no-max flash, split-K x2, PACKED fragment loads (coalesced 1KB).
// grid (32 qt, 32 hb, 2 split) x 256 thr; unroll 4, prt quad-buffer.
// ---------------------------------------------------------------------------
__global__ __launch_bounds__(256, 4) void attnA(
    const u16* __restrict__ Qp, const u16* __restrict__ Kp,
    const u16* __restrict__ wkwq, const u16* __restrict__ Vp,
    const u16* __restrict__ xxt, const float* __restrict__ Dbuf,
    u16* __restrict__ O1, u16* __restrict__ O2,
    float* __restrict__ L1, float* __restrict__ L2)
{
  __shared__ __align__(16) u16 prt[4*2560];   // [4 waves][4 bufs][640]
  const int tid = threadIdx.x;
  const int lane = tid & 63, w = tid >> 6;
  const int l15 = lane & 15, quad = lane >> 4, q4 = quad*4;
  const int hb = blockIdx.y;
  const int c = hb & 15, b = hb >> 4;
  const int qt = blockIdx.x;
  const int sp = blockIdx.z;
  const int kt0 = sp * 32;
  const size_t xxbase = (size_t)b * Nx * Nx;
  const int row0 = qt*64 + w*16;

  u16* prtw = prt + w*2560;
  u16*  Osp = sp ? O2 : O1;
  float* Lsp = sp ? L2 : L1;
  const int mtd = (row0 >> 5) - kt0;          // only this iter can hit diagonal

  // packed bases (lane-linear units of 512 u16)
  const int r16 = b*128 + qt*4 + w;
  const u16* QpB = Qp + ((size_t)((r16*16 + c)*2))*512 + lane*8;
  const u16* KpB = Kp + ((size_t)(c*128 + b*64 + kt0)*4)*512 + lane*8;
  const u16* VpB = Vp + ((size_t)(((b*16 + c)*64 + kt0)*4))*512 + lane*8;

  short8 qf[2];
  #pragma unroll
  for (int s = 0; s < 2; ++s) qf[s] = *(const short8*)&QpB[s*512];
  float dv[4];
  #pragma unroll
  for (int r = 0; r < 4; ++r) dv[r] = Dbuf[b*2048 + row0 + q4 + r];
  const float wkh = bf2f(wkwq[c]) * L2E;

  f32x4 O[4] = {};
  float lrun[4] = {0.f, 0.f, 0.f, 0.f};
  const u16* pxx = xxt + xxbase + (size_t)(row0 + q4)*Nx + kt0*32 + l15;

  #pragma unroll 4
  for (int mt = 0; mt < 32; ++mt) {
    u16* pw = prtw + (mt & 3)*640;            // quad-buffer
    float xb[2][4];
    #pragma unroll
    for (int s = 0; s < 2; ++s)
      #pragma unroll
      for (int r = 0; r < 4; ++r)
        xb[s][r] = bf2f(pxx[r*Nx + s*16]);
    short8 kf[2][2];
    #pragma unroll
    for (int s = 0; s < 2; ++s)
      #pragma unroll
      for (int k2 = 0; k2 < 2; ++k2)
        kf[s][k2] = *(const short8*)&KpB[(mt*4 + s*2 + k2)*512];
    short8 vf[4];
    #pragma unroll
    for (int dt = 0; dt < 4; ++dt)
      vf[dt] = *(const short8*)&VpB[(mt*4 + dt)*512];
    f32x4 t2[2];
    #pragma unroll
    for (int s = 0; s < 2; ++s){
      f32x4 t = {};
      t = MFMA(qf[0], kf[s][0], t);
      t = MFMA(qf[1], kf[s][1], t);
      t2[s] = t;
    }
    if (mt == mtd) {                          // wave-uniform branch
      const int kb = (kt0 + mt)*32 + l15;
      #pragma unroll
      for (int s = 0; s < 2; ++s)
        #pragma unroll
        for (int r = 0; r < 4; ++r){
          const int ng = row0 + q4 + r;
          float bias = (kb + s*16 == ng) ? dv[r] : xb[s][r];
          float p = exp2f(t2[s][r] + wkh*bias);
          lrun[r] += p;
          pw[(q4+r)*40 + s*16 + l15] = f2bf(p);
        }
    } else {
      #pragma unroll
      for (int s = 0; s < 2; ++s)
        #pragma unroll
        for (int r = 0; r < 4; ++r){
          float p = exp2f(t2[s][r] + wkh*xb[s][r]);
          lrun[r] += p;
          pw[(q4+r)*40 + s*16 + l15] = f2bf(p);
        }
    }
    short8 pf = lds8(&pw[l15*40 + quad*8]);
    #pragma unroll
    for (int dt = 0; dt < 4; ++dt) O[dt] = MFMA(pf, vf[dt], O[dt]);
    pxx += 32;
  }

  // cross-lane l sum (within the 16-lane group owning these rows)
  #pragma unroll
  for (int r = 0; r < 4; ++r){
    float l = lrun[r];
    l += __shfl_xor(l, 1); l += __shfl_xor(l, 2);
    l += __shfl_xor(l, 4); l += __shfl_xor(l, 8);
    lrun[r] = l;
  }
  #pragma unroll
  for (int dt = 0; dt < 4; ++dt)
    #pragma unroll
    for (int r = 0; r < 4; ++r)
      Osp[(size_t)(b*2048 + row0 + q4 + r)*1024 + c*64 + dt*16 + l15]
        = f2bf(O[dt][r]);
  if (l15 == 0){
    #pragma unroll
    for (int r = 0; r < 4; ++r)
      Lsp[(size_t)(b*2048 + row0 + q4 + r)*16 + c] = lrun[r];
  }
}

// ---------------------------------------------------------------------------
// attnM: merge splits. Obuf = (O1+O2) * il,  il = 1/(l1+l2); emit Sil.
// ---------------------------------------------------------------------------
__global__ __launch_bounds__(128) void attnM(
    const u16* __restrict__ O1, const u16* __restrict__ O2,
    const float* __restrict__ L1, const float* __restrict__ L2,
    u16* __restrict__ Obuf, float* __restrict__ Sil)
{
  const int row = blockIdx.x;
  const int t = threadIdx.x;
  const int h = t >> 3;
  const float il = 1.0f / fmaxf(L1[(size_t)row*16 + h] + L2[(size_t)row*16 + h], 1e-30f);
  short8 a = *(const short8*)&O1[(size_t)row*1024 + t*8];
  short8 b = *(const short8*)&O2[(size_t)row*1024 + t*8];
  ushort8 o;
  #pragma unroll
  for (int j = 0; j < 8; ++j)
    o[j] = f2bf((bf2f((u16)a[j]) + bf2f((u16)b[j])) * il);
  *(ushort8*)&Obuf[(size_t)row*1024 + t*8] = o;
  if ((t & 7) == 0) Sil[(size_t)row*16 + h] = il;
}

// ---------------------------------------------------------------------------
// attnB: PSA[b][q][k] = sum_h wvh*il_h*exp2(sv_h), 64x64 tiles, PACKED loads.
// grid (32 kt, 32 qt, 2 b) x 256 thr.
// ---------------------------------------------------------------------------
__global__ __launch_bounds__(256, 4) void attnB(
    const u16* __restrict__ Qp, const u16* __restrict__ Kp,
    const u16* __restrict__ wkwq, const u16* __restrict__ wvwo,
    const u16* __restrict__ xxt, const float* __restrict__ Sil,
    const float* __restrict__ Dbuf, u16* __restrict__ PSA)
{
  __shared__ float sst[1024];                // [64 rows][16 h] il
  const int tid = threadIdx.x;
  const int lane = tid & 63, w = tid >> 6;
  const int l15 = lane & 15, quad = lane >> 4, q4 = quad*4;
  const int kt = blockIdx.x, qt = blockIdx.y, b = blockIdx.z;
  const size_t xxbase = (size_t)b * Nx * Nx;

  {
    const float* src = Sil + ((size_t)b*2048 + qt*64)*16;
    for (int i = tid; i < 1024; i += 256) sst[i] = src[i];
  }
  __syncthreads();

  const int rloc = w*16 + q4;
  float xbv[4][4];
  #pragma unroll
  for (int ks = 0; ks < 4; ++ks)
    #pragma unroll
    for (int r = 0; r < 4; ++r){
      int gr = qt*64 + rloc + r;
      int gc = kt*64 + ks*16 + l15;
      float v = bf2f(xxt[xxbase + (size_t)gr*Nx + gc]);
      if (gr == gc) v = Dbuf[b*2048 + gr];
      xbv[ks][r] = v;
    }

  const int r16 = b*128 + qt*4 + w;
  const u16* QpB = Qp + lane*8;
  const u16* KpB = Kp + lane*8;

  f32x4 psa_[4] = {};
  #pragma unroll 2
  for (int h = 0; h < 16; ++h){
    const float wkh = bf2f(wkwq[h]) * L2E;
    const float wvh = bf2f(wvwo[h]);
    short8 qf[2];
    #pragma unroll
    for (int s = 0; s < 2; ++s)
      qf[s] = *(const short8*)&QpB[((size_t)((r16*16 + h)*2 + s))*512];
    short8 kf[4][2];
    #pragma unroll
    for (int ks = 0; ks < 4; ++ks)
      #pragma unroll
      for (int k2 = 0; k2 < 2; ++k2){
        int g32 = b*64 + kt*2 + (ks >> 1);
        kf[ks][k2] = *(const short8*)&KpB[((size_t)((h*128 + g32)*4 + (ks&1)*2 + k2))*512];
      }
    #pragma unroll
    for (int ks = 0; ks < 4; ++ks){
      f32x4 t = {};
      t = MFMA(qf[0], kf[ks][0], t);
      t = MFMA(qf[1], kf[ks][1], t);
      #pragma unroll
      for (int r = 0; r < 4; ++r){
        float ilw = sst[(rloc + r)*16 + h] * wvh;
        psa_[ks][r] += exp2f(t[r] + wkh*xbv[ks][r]) * ilw;
      }
    }
  }
  #pragma unroll
  for (int ks = 0; ks < 4; ++ks)
    #pragma unroll
    for (int r = 0; r < 4; ++r)
      PSA[(size_t)(b*2048 + qt*64 + rloc + r)*Nx + kt*64 + ks*16 + l15]
        = f2bf(psa_[ks][r]);
}

// ---------------------------------------------------------------------------
// attn2 (v13 path, verified) — fallback if ws in [16MB, NEED)
// ---------------------------------------------------------------------------
#define B_PRT 0
#define B_PSP 20480
#define B_DG  61440
#define B_SZ  86016

__global__ __launch_bounds__(1024)
__attribute__((amdgpu_waves_per_eu(4, 4)))
void attn2(
    const u16* __restrict__ x, const u16* __restrict__ wq,
    const u16* __restrict__ wo, const u16* __restrict__ wkwq,
    const u16* __restrict__ wvwo, const u16* __restrict__ K16,
    const u16* __restrict__ Vb0, const u16* __restrict__ Vb1a,
    const u16* __restrict__ Vb1b, u16* __restrict__ PSA,
    float* out)
{
  __shared__ __align__(16) u8 AR[B_SZ];
  const int tid = threadIdx.x;
  const int lane = tid & 63, c = tid >> 6;
  const int l15 = lane & 15, quad = lane >> 4, q4 = quad*4;
  int bb = blockIdx.x; bb = (bb & 7)*32 + (bb >> 3);
  const int b = bb >> 7, n0 = (bb & 127) * 16;
  const size_t xbase = (size_t)b * Nx * Dx;
  const u16* xxt = (const u16*)out;
  const size_t xxbase = (size_t)b * Nx * Nx;
  u16* psag = PSA + (size_t)b * Nx * Nx;

  u16*   prt = (u16*)(AR + B_PRT);
  u16*   psp = (u16*)(AR + B_PSP);
  float* dgv = (float*)(AR + B_DG);
  u16*   qrt = (u16*)(AR + 0) + c*(16*72);

  {
    f32x4 qacc[4] = {};
    #pragma unroll 1
    for (int kc = 0; kc < 32; ++kc) {
      short8 af = *(const short8*)&x[xbase + (size_t)(n0 + l15)*Dx + kc*32 + quad*8];
      #pragma unroll
      for (int j = 0; j < 4; ++j) {
        short8 bf = *(const short8*)&wq[(size_t)(c*64 + j*16 + l15)*Dx + kc*32 + quad*8];
        qacc[j] = MFMA(af, bf, qacc[j]);
      }
    }
    const float qs = SCALEx * L2E;
    #pragma unroll
    for (int j = 0; j < 4; ++j)
      #pragma unroll
      for (int r = 0; r < 4; ++r)
        qrt[(q4+r)*72 + j*16 + l15] = f2bf(qacc[j][r] * qs);
  }
  {
    float s = 0.f;
    #pragma unroll
    for (int p = 0; p < 2; ++p) {
      short8 v = *(const short8*)&x[xbase + (size_t)(n0+c)*Dx + p*512 + lane*8];
      #pragma unroll
      for (int i = 0; i < 8; ++i){ float f = bf2f((u16)v[i]); s += f*f; }
    }
    #pragma unroll
    for (int o = 1; o < 64; o <<= 1) s += __shfl_xor(s, o);
    if (lane == 0) dgv[c] = s;
  }
  short8 qf[2];
  #pragma unroll
  for (int s = 0; s < 2; ++s) qf[s] = lds8(&qrt[l15*72 + s*32 + quad*8]);
  __syncthreads();
  float dv[4];
  #pragma unroll
  for (int r = 0; r < 4; ++r) dv[r] = dgv[q4+r];
  __syncthreads();

  const float wkh = bf2f(wkwq[c]) * L2E;
  const float wvh = bf2f(wvwo[c]);

  float mrun[4], lrun[4];
  #pragma unroll
  for (int r = 0; r < 4; ++r){ mrun[r] = -1e30f; lrun[r] = 0.f; }

  const u16* pk  = K16 + xbase + (size_t)l15*Dx + c*64;
  const u16* pxx = xxt + xxbase + (size_t)(n0+q4)*Nx + l15;

  #pragma unroll 2
  for (int mt = 0; mt < 64; ++mt) {
    float xb[2][4];
    #pragma unroll
    for (int s = 0; s < 2; ++s)
      #pragma unroll
      for (int r = 0; r < 4; ++r)
        xb[s][r] = bf2f(pxx[r*Nx + s*16]);
    short8 kf[2][2];
    #pragma unroll
    for (int s = 0; s < 2; ++s)
      #pragma unroll
      for (int k2 = 0; k2 < 2; ++k2)
        kf[s][k2] = *(const short8*)&pk[s*16*Dx + k2*32 + quad*8];
    f32x4 t2[2];
    #pragma unroll
    for (int s = 0; s < 2; ++s){
      f32x4 t = {};
      t = MFMA(qf[0], kf[s][0], t);
      t = MFMA(qf[1], kf[s][1], t);
      t2[s] = t;
    }
    const int kb = mt*32 + l15;
    #pragma unroll
    for (int r = 0; r < 4; ++r){
      const int ng = n0 + q4 + r;
      float b0 = (kb      == ng) ? dv[r] : xb[0][r];
      float b1 = (kb + 16 == ng) ? dv[r] : xb[1][r];
      float sv0 = t2[0][r] + wkh*b0;
      float sv1 = t2[1][r] + wkh*b1;
      float m2 = fmaxf(sv0, sv1);
      float mn = fmaxf(mrun[r], m2);
      lrun[r] = lrun[r]*exp2f(mrun[r]-mn) + exp2f(sv0-mn) + exp2f(sv1-mn);
      mrun[r] = mn;
    }
    pk += 32*Dx; pxx += 32;
  }
  float ms[4], il[4];
  #pragma unroll
  for (int r = 0; r < 4; ++r){
    float mr = mrun[r];
    #pragma unroll
    for (int o = 1; o < 16; o <<= 1) mr = fmaxf(mr, __shfl_xor(mr, o));
    float ls = lrun[r]*exp2f(mrun[r]-mr);
    #pragma unroll
    for (int o = 1; o < 16; o <<= 1) ls += __shfl_xor(ls, o);
    ms[r] = mr; il[r] = 1.0f/fmaxf(ls, 1e-30f);
  }

  f32x4 O[4] = {};
  const u16* vbp; int voff;
  if (b == 0){ vbp = Vb0; voff = 0; }
  else if (c < 8){ vbp = Vb1a; voff = 0; }
  else { vbp = Vb1b; voff = 512; }
  const u16* pv = vbp + (size_t)(c*64 - voff + l15)*Nx;
  pk  = K16 + xbase + (size_t)l15*Dx + c*64;
  pxx = xxt + xxbase + (size_t)(n0+q4)*Nx + l15;

  #pragma unroll 1
  for (int mt = 0; mt < 64; ++mt) {
    float xb[2][4];
    #pragma unroll
    for (int s = 0; s < 2; ++s)
      #pragma unroll
      for (int r = 0; r < 4; ++r)
        xb[s][r] = bf2f(pxx[r*Nx + s*16]);
    short8 kf[2][2];
    #pragma unroll
    for (int s = 0; s < 2; ++s)
      #pragma unroll
      for (int k2 = 0; k2 < 2; ++k2)
        kf[s][k2] = *(const short8*)&pk[s*16*Dx + k2*32 + quad*8];
    short8 vf[4];
    #pragma unroll
    for (int dt = 0; dt < 4; ++dt)
      vf[dt] = *(const short8*)&pv[dt*16*Nx + quad*8];
    f32x4 t2[2];
    #pragma unroll
    for (int s = 0; s < 2; ++s){
      f32x4 t = {};
      t = MFMA(qf[0], kf[s][0], t);
      t = MFMA(qf[1], kf[s][1], t);
      t2[s] = t;
    }
    const int kb = mt*32 + l15;
    u16* pspw = psp + (mt & 1)*10240;
    #pragma unroll
    for (int s = 0; s < 2; ++s)
      #pragma unroll
      for (int r = 0; r < 4; ++r){
        const int ng = n0 + q4 + r;
        float bias = (kb + s*16 == ng) ? dv[r] : xb[s][r];
        float sv = t2[s][r] + wkh*bias;
        float p = exp2f(fminf(sv - ms[r], 0.f)) * il[r];
        prt[c*640 + (q4+r)*40 + s*16 + l15] = f2bf(p);
        pspw[c*640 + (q4+r)*40 + s*16 + l15] = f2bf(wvh * p);
      }
    short8 pf = lds8(&prt[c*640 + l15*40 + quad*8]);
    #pragma unroll
    for (int dt = 0; dt < 4; ++dt) O[dt] = MFMA(pf, vf[dt], O[dt]);
    __syncthreads();
    if (tid < 512){
      const int qq = tid >> 5, mm = tid & 31;
      float v = 0.f;
      #pragma unroll
      for (int w = 0; w < 16; ++w) v += bf2f(pspw[w*640 + qq*40 + mm]);
      psag[(size_t)(n0 + qq)*Nx + mt*32 + mm] = f2bf(v);
    }
    pk += 32*Dx; pxx += 32; pv += 32;
  }

  __syncthreads();
  u16* ol = (u16*)(AR + 0);
  #pragma unroll
  for (int dt = 0; dt < 4; ++dt)
    #pragma unroll
    for (int r = 0; r < 4; ++r)
      ol[(q4+r)*1040 + c*64 + dt*16 + l15] = f2bf(O[dt][r]);
  __syncthreads();
  f32x4 Uo[4] = {};
  #pragma unroll 1
  for (int kc = 0; kc < 32; ++kc){
    short8 af = lds8(&ol[l15*1040 + kc*32 + quad*8]);
    #pragma unroll
    for (int ct = 0; ct < 4; ++ct){
      short8 bw = *(const short8*)&wo[(size_t)(c*64 + ct*16 + l15)*Dx + kc*32 + quad*8];
      Uo[ct] = MFMA(af, bw, Uo[ct]);
    }
  }
  #pragma unroll
  for (int ct = 0; ct < 4; ++ct)
    #pragma unroll
    for (int r = 0; r < 4; ++r)
      out[xbase + (size_t)(n0+q4+r)*Dx + c*64 + ct*16 + l15] = Uo[ct][r];
}

// ---------------------------------------------------------------------------
extern "C" void kernel_launch(void* const* d_in, const int* in_sizes, int n_in,
                              void* d_out, int out_size, void* d_ws, size_t ws_size,
                              hipStream_t stream) {
  u16* x16   = (u16*)d_in[0];
  u16* K16   = x16 + 4u*1024u*1024u;           // Kp (packed) in main path
  u16* wqk16 = (u16*)d_in[1];
  u16* Vb0   = wqk16 + 2u*1024u*1024u;
  u16* wv16  = (u16*)d_in[2];
  u16* Vb1a  = wv16 + 1024u*1024u;
  u16* wo16  = (u16*)d_in[3];
  u16* Vb1b  = wo16 + 1024u*1024u;
  float* outF = (float*)d_out;
  u16* S = (u16*)d_out;

  const float loW = 0.000244140625f, hiW = 0.25f;
  conv_w<<<dim3(512), 256, 0, stream>>>(d_in[0], S, 4*1024*1024, 512, 0.00390625f, 16.0f);
  copyb <<<dim3(512), 256, 0, stream>>>(S, x16, 4*1024*1024);
  conv_w<<<dim3(256), 256, 0, stream>>>(d_in[1], S, 2*1024*1024, 512, loW, hiW);
  copyb <<<dim3(256), 256, 0, stream>>>(S, wqk16, 2*1024*1024);
  conv_w<<<dim3(128), 256, 0, stream>>>(d_in[2], S, 1024*1024, 512, loW, hiW);
  copyb <<<dim3(128), 256, 0, stream>>>(S, wv16, 1024*1024);
  conv_w<<<dim3(128), 256, 0, stream>>>(d_in[3], S, 1024*1024, 512, loW, hiW);
  copyb <<<dim3(128), 256, 0, stream>>>(S, wo16, 1024*1024);
  conv_small<<<dim3(1), 64, 0, stream>>>((void*)d_in[4], 16, loW, hiW);
  conv_small<<<dim3(1), 64, 0, stream>>>((void*)d_in[5], 16, loW, hiW);

  // ws layout (bytes)
  const size_t OFF_PSA = 0;              // 16 MB
  const size_t OFF_Q   = 16777216;       //  8 MB (Qp packed)
  const size_t OFF_OB  = 25165824;       //  8 MB (normalized O)
  const size_t OFF_O1  = 33554432;       //  8 MB
  const size_t OFF_O2  = 41943040;       //  8 MB
  const size_t OFF_VP  = 50331648;       //  8 MB (Vp packed)
  const size_t OFF_L1  = 58720256;       // 256 KB
  const size_t OFF_L2  = 58982400;       // 256 KB
  const size_t OFF_SI  = 59244544;       // 256 KB
  const size_t OFF_D   = 59506688;       //  16 KB
  const size_t NEED    = 59523072;

  // XXT = x @ x^T (bf16) into d_out (common to both paths)
  gemm_bf16<<<dim3(16, 16), 256, 0, stream>>>(x16,               x16,               (u16*)d_out,                  2048, 1.0f);
  gemm_bf16<<<dim3(16, 16), 256, 0, stream>>>(x16 + 2048u*1024u, x16 + 2048u*1024u, (u16*)d_out + 4u*1024u*1024u, 2048, 1.0f);

  if (d_ws != nullptr && ws_size >= NEED) {
    u8* ws = (u8*)d_ws;
    // packed K / V / Q (fragment-order epilogues; zero extra traffic)
    gemm_kpack<<<dim3(8, 32), 256, 0, stream>>>(x16, wqk16 + 1024u*1024u, K16);
    gemm_vpack<<<dim3(16, 8), 256, 0, stream>>>(wv16, x16,               (u16*)(ws + OFF_VP), 0);
    gemm_vpack<<<dim3(16, 8), 256, 0, stream>>>(wv16, x16 + 2048u*1024u, (u16*)(ws + OFF_VP), 1);
    gemm_qpack<<<dim3(8, 32), 256, 0, stream>>>(x16, wqk16, (u16*)(ws + OFF_Q), SCALEx * L2E);
    diag_k<<<dim3(32, 2), 256, 0, stream>>>(x16, (float*)(ws + OFF_D));
    attnA<<<dim3(32, 32, 2), 256, 0, stream>>>(
        (const u16*)(ws + OFF_Q), K16, (const u16*)d_in[4],
        (const u16*)(ws + OFF_VP), (const u16*)d_out, (const float*)(ws + OFF_D),
        (u16*)(ws + OFF_O1), (u16*)(ws + OFF_O2),
        (float*)(ws + OFF_L1), (float*)(ws + OFF_L2));
    attnM<<<dim3(4096), 128, 0, stream>>>(
        (const u16*)(ws + OFF_O1), (const u16*)(ws + OFF_O2),
        (const float*)(ws + OFF_L1), (const float*)(ws + OFF_L2),
        (u16*)(ws + OFF_OB), (float*)(ws + OFF_SI));
    attnB<<<dim3(32, 32, 2), 256, 0, stream>>>(
        (const u16*)(ws + OFF_Q), K16, (const u16*)d_in[4], (const u16*)d_in[5],
        (const u16*)d_out, (const float*)(ws + OFF_SI), (const float*)(ws + OFF_D),
        (u16*)(ws + OFF_PSA));
    gemm_nt_f32<<<dim3(8, 32), 256, 0, stream>>>((const u16*)(ws + OFF_OB), wo16, outF);
    gemm_nn_add<<<dim3(8, 16, 2), 256, 0, stream>>>((const u16*)(ws + OFF_PSA), x16, outF);
  } else if (d_ws != nullptr && ws_size >= (size_t)2*2048*2048*2) {
    // fallback: linear K/V layouts + verified attn2
    gemm_bf16<<<dim3(8, 32), 256, 0, stream>>>(x16, wqk16 + 1024u*1024u, K16, 1024, 1.0f);
    gemm_bf16<<<dim3(16, 8), 256, 0, stream>>>(wv16, x16, Vb0, 2048, 1.0f);
    gemm_bf16<<<dim3(16, 4), 256, 0, stream>>>(wv16,              x16 + 2048u*1024u, Vb1a, 2048, 1.0f);
    gemm_bf16<<<dim3(16, 4), 256, 0, stream>>>(wv16 + 512u*1024u, x16 + 2048u*1024u, Vb1b, 2048, 1.0f);
    attn2<<<dim3(256), 1024, 0, stream>>>(x16, wqk16, wo16,
        (const u16*)d_in[4], (const u16*)d_in[5], K16, Vb0, Vb1a, Vb1b,
        (u16*)d_ws, outF);
    gemm_nn_add<<<dim3(8, 16, 2), 256, 0, stream>>>((const u16*)d_ws, x16, outF);
  }
}